// Round 4
// baseline (502.078 us; speedup 1.0000x reference)
//
#include <hip/hip_runtime.h>
#include <hip/hip_bf16.h>

// Bilinear multi-head self-attention, MI355X
#define KH 16    // heads
#define PD 1024  // value-in dim
#define QD 1024  // out dim
#define DD 64    // head dim
#define BB 2     // batch
#define NN 2048  // seq len
#define BN 4096  // BB*NN rows
#define ST 72    // padded LDS row stride (u16) for attn
#define SOFT_C 12.0f  // fixed softmax offset: exact (cancels in p/sum p)
#define LOG2E 1.4426950408889634f
#define SOFT_C2 17.312340490667560f  // SOFT_C * log2(e)

typedef unsigned short u16;
typedef __attribute__((ext_vector_type(8))) short bf16x8;  // K=32 A/B frag
typedef __attribute__((ext_vector_type(4))) short bf16x4;  // K=16 A/B frag
typedef __attribute__((ext_vector_type(4))) float f32x4;   // C/D frag

__device__ __forceinline__ float bf2f(u16 u) {
    return __uint_as_float(((unsigned)u) << 16);
}
__device__ __forceinline__ u16 f2bf(float f) {
    unsigned x = __float_as_uint(f);
    x += 0x7FFFu + ((x >> 16) & 1u);  // RNE
    return (u16)(x >> 16);
}
__device__ __forceinline__ f32x4 mfma_k32(bf16x8 a, bf16x8 b, f32x4 c) {
    return __builtin_amdgcn_mfma_f32_16x16x32_bf16(a, b, c, 0, 0, 0);
}
// padded-layout frag (attn K)
__device__ __forceinline__ bf16x8 ldfrag(const u16* base, int r0, int kc, int lane) {
    return *reinterpret_cast<const bf16x8*>(base + (r0 + (lane & 15)) * ST + kc +
                                            ((lane >> 4) << 3));
}
// linear-layout frag (GEMMs, stride 64 u16 — required by global_load_lds DMA)
__device__ __forceinline__ bf16x8 ldfragL(const u16* base, int r0, int kc, int lane) {
    return *reinterpret_cast<const bf16x8*>(base + ((r0 + (lane & 15)) << 6) + kc +
                                            ((lane >> 4) << 3));
}
__device__ __forceinline__ bf16x4 pack4(float a, float b, float c, float d) {
    union { bf16x4 v; __hip_bfloat162 h[2]; } u;
    u.h[0] = __float22bfloat162_rn(make_float2(a, b));
    u.h[1] = __float22bfloat162_rn(make_float2(c, d));
    return u.v;
}
// async global->LDS DMA, 16B/lane; LDS dst = wave-uniform base + lane*16
__device__ __forceinline__ void gl_lds16(const u16* g, u16* l) {
    __builtin_amdgcn_global_load_lds(
        (const __attribute__((address_space(1))) void*)g,
        (__attribute__((address_space(3))) void*)l, 16, 0, 0);
}
// stage ROWSx64 tile (row stride ld) into LINEAR LDS via DMA; 256 threads
template <int ROWS>
__device__ __forceinline__ void stage_dma(const u16* __restrict__ src, int ld,
                                          u16* dst, int lane, int w) {
#pragma unroll
    for (int c = 0; c < ROWS / 32; ++c) {
        int rbase = (w * (ROWS / 32) + c) * 8;
        const u16* g = src + (size_t)(rbase + (lane >> 3)) * ld + ((lane & 7) << 3);
        gl_lds16(g, dst + (rbase << 6));
    }
}

// ---------------------------------------------------------------------------
// dtype detector (+ init mask-nonzero flag to 0)
__global__ void detect_kernel(const u16* __restrict__ y, int* flag, int* mnz) {
    __shared__ int cnt;
    if (threadIdx.x == 0) cnt = 0;
    __syncthreads();
    int local = 0;
    for (int i = threadIdx.x; i < 8192; i += 256) {
        u16 u = y[i];
        int e = (u >> 7) & 0xFF;
        if (u == 0 || (e >= 96 && e < 160)) local++;
    }
    atomicAdd(&cnt, local);
    __syncthreads();
    if (threadIdx.x == 0) {
        *flag = (cnt > 7372) ? 1 : 0;
        *mnz = 0;
    }
}

// mask nonzero scan (bitwise OR of raw words — dtype-independent for zero)
__global__ __launch_bounds__(256) void scan_kernel(const void* __restrict__ msrc,
                                                   const int* __restrict__ flag,
                                                   int* __restrict__ mnz) {
    size_t n4 = (size_t)NN * NN / 8;
    if (!*flag) n4 *= 2;
    const uint4* p = (const uint4*)msrc;
    unsigned acc = 0;
    for (size_t i = (size_t)blockIdx.x * 256 + threadIdx.x; i < n4; i += 256 * 256) {
        uint4 v = p[i];
        acc |= v.x | v.y | v.z | v.w;
    }
    if (acc) atomicOr(mnz, 1);
}

// ---------------------------------------------------------------------------
// fused prepass: grid (256, 1, 6), block 256.
// z=0: convert y; z=1..3: convert+transpose weights ([KH][PD][DD]->
// [KH][DD][PD], LamY prescaled 0.125); z=4: ThY rearrange ([KH][QD][DD]->
// [QD][KH*DD]); z=5: mask convert+prescale (skipped when mask==0).
__global__ __launch_bounds__(256) void prep_kernel(
    const void* __restrict__ ysrc, const void* __restrict__ msrc,
    const void* __restrict__ s0, const void* __restrict__ s1,
    const void* __restrict__ s2, const void* __restrict__ s3,
    u16* __restrict__ ycan, u16* __restrict__ LamXt, u16* __restrict__ LamYt,
    u16* __restrict__ ThXt, u16* __restrict__ ThYr, u16* __restrict__ maskc,
    const int* __restrict__ flag, const int* __restrict__ mnz) {
    int z = blockIdx.z, bx = blockIdx.x, tid = threadIdx.x;
    int isbf = *flag;
    if (z == 0) {  // convert y'
        int n = BN * PD;
        for (int i = (bx * 256 + tid) * 4; i < n; i += 256 * 256 * 4) {
            if (isbf) {
                *reinterpret_cast<uint2*>(ycan + i) =
                    *reinterpret_cast<const uint2*>((const u16*)ysrc + i);
            } else {
                float4 f = *reinterpret_cast<const float4*>((const float*)ysrc + i);
                u16 t[4] = {f2bf(f.x), f2bf(f.y), f2bf(f.z), f2bf(f.w)};
                *reinterpret_cast<uint2*>(ycan + i) = *reinterpret_cast<uint2*>(t);
            }
        }
    } else if (z <= 3) {  // weight transpose
        const void* src = (z == 1) ? s0 : (z == 2) ? s1 : s2;
        u16* dst = (z == 1) ? LamXt : (z == 2) ? LamYt : ThXt;
        float scale = (z == 2) ? 0.125f : 1.0f;
        int k = bx >> 4, p0 = (bx & 15) * 64;
        __shared__ float T[64][65];
        const u16* s16 = (const u16*)src + ((size_t)k * PD + p0) * DD;
        const float* s32 = (const float*)src + ((size_t)k * PD + p0) * DD;
#pragma unroll
        for (int it = 0; it < 2; ++it) {
            int chunk = it * 256 + tid;
            int row = chunk >> 3, c8 = (chunk & 7) << 3;
            float f[8];
            if (isbf) {
                uint4 v = *reinterpret_cast<const uint4*>(s16 + row * DD + c8);
                u16 t[8];
                *reinterpret_cast<uint4*>(t) = v;
#pragma unroll
                for (int e = 0; e < 8; ++e) f[e] = bf2f(t[e]);
            } else {
                float4 a = *reinterpret_cast<const float4*>(s32 + row * DD + c8);
                float4 b = *reinterpret_cast<const float4*>(s32 + row * DD + c8 + 4);
                f[0] = a.x; f[1] = a.y; f[2] = a.z; f[3] = a.w;
                f[4] = b.x; f[5] = b.y; f[6] = b.z; f[7] = b.w;
            }
#pragma unroll
            for (int e = 0; e < 8; ++e) T[row][c8 + e] = f[e] * scale;
        }
        __syncthreads();
        u16* drow = dst + (size_t)k * DD * PD + p0;
#pragma unroll
        for (int it = 0; it < 2; ++it) {
            int chunk = it * 256 + tid;
            int d = chunk >> 3, c8 = (chunk & 7) << 3;
            u16 t[8];
#pragma unroll
            for (int e = 0; e < 8; ++e) t[e] = f2bf(T[c8 + e][d]);
            *reinterpret_cast<uint4*>(drow + (size_t)d * PD + c8) =
                *reinterpret_cast<uint4*>(t);
        }
    } else if (z == 4) {  // ThY rearrange
        int k = bx >> 4, q0 = (bx & 15) * 64;
#pragma unroll
        for (int it = 0; it < 2; ++it) {
            int chunk = it * 256 + tid;
            int row = chunk >> 3, c8 = (chunk & 7) << 3;
            size_t si = ((size_t)k * QD + q0 + row) * DD + c8;
            u16 t[8];
            if (isbf) {
                *reinterpret_cast<uint4*>(t) =
                    *reinterpret_cast<const uint4*>((const u16*)s3 + si);
            } else {
                float4 a = *reinterpret_cast<const float4*>((const float*)s3 + si);
                float4 b = *reinterpret_cast<const float4*>((const float*)s3 + si + 4);
                t[0] = f2bf(a.x); t[1] = f2bf(a.y); t[2] = f2bf(a.z); t[3] = f2bf(a.w);
                t[4] = f2bf(b.x); t[5] = f2bf(b.y); t[6] = f2bf(b.z); t[7] = f2bf(b.w);
            }
            *reinterpret_cast<uint4*>(ThYr + (size_t)(q0 + row) * (KH * DD) +
                                      k * DD + c8) = *reinterpret_cast<uint4*>(t);
        }
    } else {  // z == 5: mask convert + prescale (only if mask nonzero)
        if (*mnz == 0) return;
        size_t n8 = (size_t)NN * NN / 8;
        for (size_t c = (size_t)bx * 256 + tid; c < n8; c += 256 * 256) {
            size_t i = c * 8;
            float f[8];
            if (isbf) {
                uint4 v = *reinterpret_cast<const uint4*>((const u16*)msrc + i);
                u16 t[8];
                *reinterpret_cast<uint4*>(t) = v;
#pragma unroll
                for (int e = 0; e < 8; ++e) f[e] = bf2f(t[e]);
            } else {
                float4 a = *reinterpret_cast<const float4*>((const float*)msrc + i);
                float4 b = *reinterpret_cast<const float4*>((const float*)msrc + i + 4);
                f[0] = a.x; f[1] = a.y; f[2] = a.z; f[3] = a.w;
                f[4] = b.x; f[5] = b.y; f[6] = b.z; f[7] = b.w;
            }
            u16 t[8];
#pragma unroll
            for (int e = 0; e < 8; ++e) t[e] = f2bf(f[e] * 0.125f);
            *reinterpret_cast<uint4*>(maskc + i) = *reinterpret_cast<uint4*>(t);
        }
    }
}

// ---------------------------------------------------------------------------
// Kernel 1: projections GEMM [BN x PD] x [PD x 3072], DMA staging, linear LDS,
// LDS-staged full-line epilogue. grid (BN/128, 3072/128), block 256.
// V output (s==2) is stored FRAGMENT-MAJOR: per (head, 32-token block c,
// d-group dg) a 1KB block holding the 16x16x32 PV A-fragment in lane order
// (lane*16B), with the within-32 key permutation p = quad*8 + h*4 + r for
// token w = h*16 + quad*4 + r. attn reads each fragment as ONE coalesced
// 16B/lane load at base + lane*8 (u16).
__global__ __launch_bounds__(256, 3) void proj_gemm(
    const u16* __restrict__ A,   // ycan [BN][PD]
    const u16* __restrict__ Bm,  // Wcat [3072][PD]
    u16* __restrict__ Xk, u16* __restrict__ Yk, u16* __restrict__ Vtg) {
    int tid = threadIdx.x, lane = tid & 63, w = tid >> 6;
    int mhalf = w & 1, nhalf = w >> 1;
    int m0 = blockIdx.x * 128, n0 = blockIdx.y * 128;
    __shared__ u16 As[128 * 64];
    __shared__ u16 Bs[128 * 64];
    f32x4 acc[4][4] = {};

    for (int kk = 0; kk < PD; kk += 64) {
        __syncthreads();
        stage_dma<128>(A + (size_t)m0 * PD + kk, PD, As, lane, w);
        stage_dma<128>(Bm + (size_t)n0 * PD + kk, PD, Bs, lane, w);
        __syncthreads();
#pragma unroll
        for (int kc = 0; kc < 64; kc += 32) {
            bf16x8 af[4], bf[4];
#pragma unroll
            for (int i = 0; i < 4; ++i) af[i] = ldfragL(As, mhalf * 64 + i * 16, kc, lane);
#pragma unroll
            for (int j = 0; j < 4; ++j) bf[j] = ldfragL(Bs, nhalf * 64 + j * 16, kc, lane);
#pragma unroll
            for (int i = 0; i < 4; ++i)
#pragma unroll
                for (int j = 0; j < 4; ++j) acc[i][j] = mfma_k32(af[i], bf[j], acc[i][j]);
        }
    }
    int s = n0 >> 10;  // tile never crosses the 1024 boundary
    int quad = lane >> 4, col = lane & 15;
    u16* stg = nhalf ? Bs : As;  // this wave-pair's 128x64 output half
    __syncthreads();             // K-loop LDS reads complete
    if (s == 2) {
        // stage fragment-major: local idx = (cLoc*4 + jj)*512 + quad*128 +
        // col*8 + (i&1)*4 + r, where cLoc = mhalf*2 + (i>>1). Global copy is
        // then LINEAR (head_base + m0*64 + idx).
#pragma unroll
        for (int i = 0; i < 4; ++i)
#pragma unroll
            for (int j = 0; j < 4; ++j)
                *reinterpret_cast<bf16x4*>(stg + ((mhalf * 2 + (i >> 1)) * 4 + j) * 512 +
                                           quad * 128 + col * 8 + (i & 1) * 4) =
                    pack4(acc[i][j][0], acc[i][j][1], acc[i][j][2], acc[i][j][3]);
    } else {
        // stage as [tok 128][d 64] (linear = global layout)
#pragma unroll
        for (int i = 0; i < 4; ++i)
#pragma unroll
            for (int j = 0; j < 4; ++j)
#pragma unroll
                for (int reg = 0; reg < 4; ++reg)
                    stg[(mhalf * 64 + i * 16 + quad * 4 + reg) * 64 + j * 16 + col] =
                        f2bf(acc[i][j][reg]);
    }
    __syncthreads();
#pragma unroll
    for (int h = 0; h < 2; ++h) {
        int kh = ((n0 + h * 64) >> 6) & 15;
        const u16* src = h ? Bs : As;
        if (s == 2) {
            u16* vb = Vtg + (size_t)kh * DD * BN + (size_t)m0 * 64;
#pragma unroll
            for (int it = 0; it < 4; ++it) {
                int chunk = it * 256 + tid;  // 1024 uint4, fully linear
                *reinterpret_cast<uint4*>(vb + chunk * 8) =
                    *reinterpret_cast<const uint4*>(src + chunk * 8);
            }
        } else {
            u16* ob = (s == 0 ? Xk : Yk) + (size_t)kh * BN * DD + (size_t)m0 * DD;
#pragma unroll
            for (int it = 0; it < 4; ++it) {
                int chunk = it * 256 + tid;
                *reinterpret_cast<uint4*>(ob + chunk * 8) =
                    *reinterpret_cast<const uint4*>(src + chunk * 8);
            }
        }
    }
}

// ---------------------------------------------------------------------------
// Kernel 2a: flash attention v5 — SPLIT-K. Grid 1024 (XCD-swizzled): each
// block computes HALF the key range (16 tiles) for a 128-q tile, writing
// unnormalized f32 O-partials + l-partials; merge_kernel combines. Doubles
// independent barrier groups per CU (4 blocks x 8 waves = 32 waves/CU with
// VGPR<=64 forced) to fill the lockstep latency bubbles diagnosed in R0-R3.
// K: LDS triple buffer (reg-staged, padded). V: global frag-major via L1.
__global__ __launch_bounds__(512, 8) void attn_split(
    const u16* __restrict__ Xk,     // keys    [KH][BN][DD]
    const u16* __restrict__ Yk,     // queries [KH][BN][DD] prescaled /8
    const u16* __restrict__ Vtg,    // V frag-major [KH][BN/32][4][64*8]
    const u16* __restrict__ maskc,  // [NN][NN] bf16 prescaled /8
    const int* __restrict__ mnz,
    float* __restrict__ Opart,      // [2][KH][BB][NN][DD] f32
    float* __restrict__ Lp) {       // [2][KH][BB][NN] f32
    int tid = threadIdx.x, lane = tid & 63, w = tid >> 6;  // w in [0,8)
    int quad = lane >> 4, col = lane & 15;
    // XCD swizzle: hw block H (XCD=H%8) -> work L; per XCD: 4 (k,b) combos,
    // all 16 q-tiles and both key-halves of each (shared K/V panels in L2).
    int H = blockIdx.x;
    int L = (H & 7) * 128 + (H >> 3);
    int half = L & 1;
    int q0 = ((L >> 1) & 15) * 128, k = (L >> 5) & 15, b = L >> 9;
    int t0 = half * 16;
    const u16* Qp = Yk + ((size_t)k * BN + b * NN + q0) * DD;
    const u16* Kp = Xk + ((size_t)k * BN + b * NN) * DD;
    const u16* Vh = Vtg + (size_t)k * DD * BN + (size_t)b * NN * 64;
    __shared__ u16 Kb[3][64 * ST];  // K triple buffer (27.6 KB total)
    int mz = *mnz;

    // Q B-frags straight from global: element j = Q[q][quad*8 + j (+32)]
    const u16* qrow = Qp + (size_t)(w * 16 + col) * DD + (quad << 3);
    bf16x8 qf0 = *reinterpret_cast<const bf16x8*>(qrow);
    bf16x8 qf1 = *reinterpret_cast<const bf16x8*>(qrow + 32);

    // K staging slot: one uint4 per thread per tile (64x64 = 512*16B)
    int srow = tid >> 3, scol = (tid & 7) << 3;
    const u16* kgp = Kp + (size_t)srow * DD + scol;
    int soff = srow * ST + scol;

    // prologue: tile t0 -> buf0; tile t0+1 load in flight
    uint4 kr = *reinterpret_cast<const uint4*>(kgp + (size_t)t0 * 64 * DD);
    *reinterpret_cast<uint4*>(Kb[0] + soff) = kr;
    kr = *reinterpret_cast<const uint4*>(kgp + (size_t)(t0 + 1) * 64 * DD);
    __syncthreads();  // buf0 visible

    float lp = 0.0f;
    f32x4 oacc[4] = {};  // O^T[d][q] d-groups

    for (int tt = 0; tt < 16; ++tt) {
        int t = t0 + tt;
        int cur = tt % 3;
        if (tt < 15) {
            int nxt = (tt + 1) % 3;
            *reinterpret_cast<uint4*>(Kb[nxt] + soff) = kr;
            __syncthreads();  // buf[nxt] visible
        }
        const u16* Ks = Kb[cur];
        // V A-frags: coalesced 1KB loads (L1-resident after first wave)
        const u16* vt = Vh + t * 4096;
        bf16x8 av[2][4];
#pragma unroll
        for (int hlf = 0; hlf < 2; ++hlf)
#pragma unroll
            for (int dg = 0; dg < 4; ++dg)
                av[hlf][dg] = *reinterpret_cast<const bf16x8*>(
                    vt + hlf * 2048 + dg * 512 + lane * 8);
        // K reg prefetch 2 tiles ahead
        if (tt < 14)
            kr = *reinterpret_cast<const uint4*>(kgp + (size_t)(t + 2) * 64 * DD);
        int m0 = t * 64;

        // S^T[key][q] = K Q^T (prescaled); exp inline per key-group
        bf16x4 pb4[4];
#pragma unroll
        for (int kg = 0; kg < 4; ++kg) {
            bf16x8 a0 = ldfrag(Ks, kg * 16, 0, lane);
            bf16x8 a1 = ldfrag(Ks, kg * 16, 32, lane);
            f32x4 s = {};
            s = mfma_k32(a0, qf0, s);
            s = mfma_k32(a1, qf1, s);
            if (mz) {
#pragma unroll
                for (int reg = 0; reg < 4; ++reg)
                    s[reg] += bf2f(
                        maskc[(size_t)(m0 + kg * 16 + quad * 4 + reg) * NN + q0 +
                              w * 16 + col]);
            }
            float p0 = exp2f(fmaf(s[0], LOG2E, -SOFT_C2));
            float p1 = exp2f(fmaf(s[1], LOG2E, -SOFT_C2));
            float p2 = exp2f(fmaf(s[2], LOG2E, -SOFT_C2));
            float p3 = exp2f(fmaf(s[3], LOG2E, -SOFT_C2));
            lp += (p0 + p1) + (p2 + p3);
            pb4[kg] = pack4(p0, p1, p2, p3);
        }
        // O^T += V^T P^T; A (frag-major V) and B (concat P) share the key
        // perm: slot (quad,j) <-> key = hlf*32 + (j>=4)*16 + quad*4 + (j&3)
#pragma unroll
        for (int hlf = 0; hlf < 2; ++hlf) {
            bf16x8 pb8 = __builtin_shufflevector(pb4[hlf * 2], pb4[hlf * 2 + 1],
                                                 0, 1, 2, 3, 4, 5, 6, 7);
#pragma unroll
            for (int dg = 0; dg < 4; ++dg)
                oacc[dg] = mfma_k32(av[hlf][dg], pb8, oacc[dg]);
        }
    }

    // epilogue: write unnormalized f32 partials (coalesced 16B stores)
    float l = lp;
    l += __shfl_xor(l, 16);
    l += __shfl_xor(l, 32);
    size_t qi = ((size_t)k * BB + b) * NN + q0 + w * 16 + col;
    if (quad == 0) Lp[(size_t)half * KH * BB * NN + qi] = l;
    float* Oph = Opart + (size_t)half * KH * BB * NN * 64 + qi * 64;
#pragma unroll
    for (int dg = 0; dg < 4; ++dg)
        *reinterpret_cast<f32x4*>(Oph + dg * 16 + quad * 4) = oacc[dg];
}

// merge: O[row][k*64+d] = (O0+O1)/(l0+l1), bf16. grid 2048 x 256.
__global__ __launch_bounds__(256) void merge_kernel(
    const float* __restrict__ Opart, const float* __restrict__ Lp,
    u16* __restrict__ O) {
    int flat = blockIdx.x * 256 + threadIdx.x;  // 524288 chunks of 8 u16
    int row = flat >> 7;
    int col8 = (flat & 127) << 3;
    int k = col8 >> 6, d0 = col8 & 63;
    int b = row >> 11, q = row & (NN - 1);
    size_t qi = ((size_t)k * BB + b) * NN + q;
    const size_t HO = (size_t)KH * BB * NN * 64;
    size_t pi = qi * 64 + d0;
    float4 a0 = *reinterpret_cast<const float4*>(Opart + pi);
    float4 a1 = *reinterpret_cast<const float4*>(Opart + pi + 4);
    float4 b0 = *reinterpret_cast<const float4*>(Opart + HO + pi);
    float4 b1 = *reinterpret_cast<const float4*>(Opart + HO + pi + 4);
    float inv = 1.0f / (Lp[qi] + Lp[KH * BB * NN + qi]);
    u16 t[8];
    t[0] = f2bf((a0.x + b0.x) * inv);
    t[1] = f2bf((a0.y + b0.y) * inv);
    t[2] = f2bf((a0.z + b0.z) * inv);
    t[3] = f2bf((a0.w + b0.w) * inv);
    t[4] = f2bf((a1.x + b1.x) * inv);
    t[5] = f2bf((a1.y + b1.y) * inv);
    t[6] = f2bf((a1.z + b1.z) * inv);
    t[7] = f2bf((a1.w + b1.w) * inv);
    *reinterpret_cast<uint4*>(O + (size_t)row * (KH * DD) + col8) =
        *reinterpret_cast<uint4*>(t);
}

// ---------------------------------------------------------------------------
// Kernel 2b: fallback full attention (R3 structure) when workspace too small
// for split-K partials. grid 512, block 512.
__global__ __launch_bounds__(512, 4) void attn_full(
    const u16* __restrict__ Xk, const u16* __restrict__ Yk,
    const u16* __restrict__ Vtg, const u16* __restrict__ maskc,
    const int* __restrict__ mnz, u16* __restrict__ O) {
    int tid = threadIdx.x, lane = tid & 63, w = tid >> 6;
    int quad = lane >> 4, col = lane & 15;
    int H = blockIdx.x;
    int L = (H & 7) * 64 + (H >> 3);
    int q0 = (L & 15) * 128, k = (L >> 4) & 15, b = L >> 8;
    const u16* Qp = Yk + ((size_t)k * BN + b * NN + q0) * DD;
    const u16* Kp = Xk + ((size_t)k * BN + b * NN) * DD;
    const u16* Vh = Vtg + (size_t)k * DD * BN + (size_t)b * NN * 64;
    __shared__ u16 Kb[3][64 * ST];
    __shared__ u16 Ost[128 * ST];
    int mz = *mnz;

    const u16* qrow = Qp + (size_t)(w * 16 + col) * DD + (quad << 3);
    bf16x8 qf0 = *reinterpret_cast<const bf16x8*>(qrow);
    bf16x8 qf1 = *reinterpret_cast<const bf16x8*>(qrow + 32);

    int srow = tid >> 3, scol = (tid & 7) << 3;
    const u16* kgp = Kp + (size_t)srow * DD + scol;
    int soff = srow * ST + scol;

    uint4 kr = *reinterpret_cast<const uint4*>(kgp);
    *reinterpret_cast<uint4*>(Kb[0] + soff) = kr;
    kr = *reinterpret_cast<const uint4*>(kgp + (size_t)64 * DD);
    __syncthreads();

    float lp = 0.0f;
    f32x4 oacc[4] = {};

    for (int t = 0; t < 32; ++t) {
        int cur = t % 3;
        if (t < 31) {
            int nxt = (t + 1) % 3;
            *reinterpret_cast<uint4*>(Kb[nxt] + soff) = kr;
            __syncthreads();
        }
        const u16* Ks = Kb[cur];
        const u16* vt = Vh + t * 4096;
        bf16x8 av[2][4];
#pragma unroll
        for (int hlf = 0; hlf < 2; ++hlf)
#pragma unroll
            for (int dg = 0; dg < 4; ++dg)
                av[hlf][dg] = *reinterpret_cast<const bf16x8*>(
                    vt + hlf * 2048 + dg * 512 + lane * 8);
        if (t < 30) kr = *reinterpret_cast<const uint4*>(kgp + (size_t)(t + 2) * 64 * DD);
        int m0 = t * 64;

        bf16x4 pb4[4];
#pragma unroll
        for (int kg = 0; kg < 4; ++kg) {
            bf16x8 a0 = ldfrag(Ks, kg * 16, 0, lane);
            bf16x8 a1 = ldfrag(Ks, kg * 16, 32, lane);
            f32x4 s = {};
            s = mfma_k32(a0, qf0, s);
            s = mfma_k32(a1, qf1, s);
            if (mz) {
#pragma unroll
                for (int reg = 0; reg < 4; ++reg)
                    s[reg] += bf2f(
                        maskc[(size_t)(m0 + kg * 16 + quad * 4 + reg) * NN + q0 +
                              w * 16 + col]);
            }
            float p0 = exp2f(fmaf(s[0], LOG2E, -SOFT_C2));
            float p1 = exp2f(fmaf(s[1], LOG2E, -SOFT_C2));
            float p2 = exp2f(fmaf(s[2], LOG2E, -SOFT_C2));
            float p3 = exp2f(fmaf(s[3], LOG2E, -SOFT_C2));
            lp += (p0 + p1) + (p2 + p3);
            pb4[kg] = pack4(p0, p1, p2, p3);
        }
#pragma unroll
        for (int hlf = 0; hlf < 2; ++hlf) {
            bf16x8 pb8 = __builtin_shufflevector(pb4[hlf * 2], pb4[hlf * 2 + 1],
                                                 0, 1, 2, 3, 4, 5, 6, 7);
#pragma unroll
            for (int dg = 0; dg < 4; ++dg)
                oacc[dg] = mfma_k32(av[hlf][dg], pb8, oacc[dg]);
        }
    }

    float l = lp;
    l += __shfl_xor(l, 16);
    l += __shfl_xor(l, 32);
    float inv = 1.0f / l;
    int q = w * 16 + col;
#pragma unroll
    for (int dg = 0; dg < 4; ++dg)
        *reinterpret_cast<bf16x4*>(Ost + q * ST + dg * 16 + quad * 4) =
            pack4(oacc[dg][0] * inv, oacc[dg][1] * inv, oacc[dg][2] * inv,
                  oacc[dg][3] * inv);
    __syncthreads();
#pragma unroll
    for (int it = 0; it < 2; ++it) {
        int chunk = it * 512 + tid;
        int row = chunk >> 3, c8 = (chunk & 7) << 3;
        *reinterpret_cast<uint4*>(O + (size_t)(b * NN + q0 + row) * (KH * DD) +
                                  k * DD + c8) =
            *reinterpret_cast<const uint4*>(Ost + row * ST + c8);
    }
}

// ---------------------------------------------------------------------------
// Kernel 3: output projection GEMM [BN x 1024] x [1024 x QD], DMA staging,
// fp32 epilogue staged through LDS for full-line writes.
// grid (BN/128, QD/128), block 256.
__global__ __launch_bounds__(256, 3) void out_gemm(
    const u16* __restrict__ A,   // Ob [BN][KH*DD]
    const u16* __restrict__ Bm,  // ThYr [QD][KH*DD]
    const int* __restrict__ flag,
    void* __restrict__ outv) {
    int tid = threadIdx.x, lane = tid & 63, w = tid >> 6;
    int mhalf = w & 1, nhalf = w >> 1;
    int m0 = blockIdx.x * 128, n0 = blockIdx.y * 128;
    __shared__ u16 S[2][128 * 64];  // As | Bs; reused as fp32 stage (32KB)
    u16* As = S[0];
    u16* Bs = S[1];
    f32x4 acc[4][4] = {};

    for (int kk = 0; kk < KH * DD; kk += 64) {
        __syncthreads();
        stage_dma<128>(A + (size_t)m0 * (KH * DD) + kk, KH * DD, As, lane, w);
        stage_dma<128>(Bm + (size_t)n0 * (KH * DD) + kk, KH * DD, Bs, lane, w);
        __syncthreads();
#pragma unroll
        for (int kc = 0; kc < 64; kc += 32) {
            bf16x8 af[4], bf[4];
#pragma unroll
            for (int i = 0; i < 4; ++i) af[i] = ldfragL(As, mhalf * 64 + i * 16, kc, lane);
#pragma unroll
            for (int j = 0; j < 4; ++j) bf[j] = ldfragL(Bs, nhalf * 64 + j * 16, kc, lane);
#pragma unroll
            for (int i = 0; i < 4; ++i)
#pragma unroll
                for (int j = 0; j < 4; ++j) acc[i][j] = mfma_k32(af[i], bf[j], acc[i][j]);
        }
    }
    int isbf = *flag;
    int quad = lane >> 4, col = lane & 15;
    if (isbf) {
#pragma unroll
        for (int i = 0; i < 4; ++i)
#pragma unroll
            for (int j = 0; j < 4; ++j)
#pragma unroll
                for (int reg = 0; reg < 4; ++reg) {
                    size_t row = m0 + mhalf * 64 + i * 16 + quad * 4 + reg;
                    int c = n0 + nhalf * 64 + j * 16 + col;
                    ((u16*)outv)[row * QD + c] = f2bf(acc[i][j][reg]);
                }
    } else {
        float* Sf = (float*)&S[0][0];  // 64 rows x 128 f32 (32KB)
#pragma unroll
        for (int h = 0; h < 2; ++h) {
            __syncthreads();  // K-loop frag reads / previous copy done
            if (mhalf == h) {
#pragma unroll
                for (int i = 0; i < 4; ++i)
#pragma unroll
                    for (int j = 0; j < 4; ++j)
#pragma unroll
                        for (int reg = 0; reg < 4; ++reg)
                            Sf[(i * 16 + quad * 4 + reg) * 128 + nhalf * 64 +
                               j * 16 + col] = acc[i][j][reg];
            }
            __syncthreads();
            float* orow = (float*)outv + (size_t)(m0 + h * 64) * QD + n0;
#pragma unroll
            for (int it = 0; it < 8; ++it) {
                int chunk = it * 256 + tid;  // 2048 chunks of 4 f32
                int row = chunk >> 5, c4 = (chunk & 31) * 4;
                *reinterpret_cast<float4*>(orow + (size_t)row * QD + c4) =
                    *reinterpret_cast<const float4*>(Sf + row * 128 + c4);
            }
        }
    }
}

// ---------------------------------------------------------------------------
extern "C" void kernel_launch(void* const* d_in, const int* in_sizes, int n_in,
                              void* d_out, int out_size, void* d_ws, size_t ws_size,
                              hipStream_t stream) {
    // ws: flag|mnz 64B; ycan 8.39M (-> Ob after proj); Wcat 3x2.1M; ThYr 2.1M;
    // Xk/Yk/Vtg 8.39M each; maskc 8.39M; Opart 33.6M; Lp 0.52M  => ~84.4 MB
    char* wsb = (char*)d_ws;
    int* flag = (int*)wsb;
    int* mnz = (int*)(wsb + 16);
    u16* ycan = (u16*)(wsb + 64);
    const size_t NYP = (size_t)BN * PD;
    const size_t NW = (size_t)KH * PD * DD;
    const size_t OSZ = (size_t)BN * KH * DD;
    u16* Wcat = ycan + NYP;  // LamXt | LamYt/8 | ThXt contiguous
    u16* ThYr = Wcat + 3 * NW;
    u16* Xk = ThYr + NW;
    u16* Yk = Xk + OSZ;
    u16* Vtg = Yk + OSZ;
    u16* maskc = Vtg + OSZ;
    u16* Ob = ycan;  // aliases ycan (dead after proj_gemm)
    float* Opart = (float*)(maskc + (size_t)NN * NN);
    float* Lp = Opart + 2 * (size_t)KH * BB * NN * 64;
    size_t need = (size_t)((char*)(Lp + 2 * (size_t)KH * BB * NN) - wsb);
    bool split = ws_size >= need;

    detect_kernel<<<1, 256, 0, stream>>>((const u16*)d_in[0], flag, mnz);
    scan_kernel<<<256, 256, 0, stream>>>(d_in[1], flag, mnz);
    prep_kernel<<<dim3(256, 1, 6), 256, 0, stream>>>(
        d_in[0], d_in[1], d_in[2], d_in[3], d_in[4], d_in[5], ycan, Wcat,
        Wcat + NW, Wcat + 2 * NW, ThYr, maskc, flag, mnz);
    proj_gemm<<<dim3(BN / 128, 3072 / 128), 256, 0, stream>>>(ycan, Wcat, Xk, Yk, Vtg);
    if (split) {
        attn_split<<<1024, 512, 0, stream>>>(Xk, Yk, Vtg, maskc, mnz, Opart, Lp);
        merge_kernel<<<2048, 256, 0, stream>>>(Opart, Lp, Ob);
    } else {
        attn_full<<<512, 512, 0, stream>>>(Xk, Yk, Vtg, maskc, mnz, Ob);
    }
    out_gemm<<<dim3(BN / 128, QD / 128), 256, 0, stream>>>(Ob, ThYr, flag, d_out);
}

// Round 5
// 246.190 us; speedup vs baseline: 2.0394x; 2.0394x over previous
//
#include <hip/hip_runtime.h>
#include <hip/hip_bf16.h>

// Bilinear multi-head self-attention, MI355X
#define KH 16    // heads
#define PD 1024  // value-in dim
#define QD 1024  // out dim
#define DD 64    // head dim
#define BB 2     // batch
#define NN 2048  // seq len
#define BN 4096  // BB*NN rows
#define ST 72    // padded LDS row stride (u16) for attn
#define SOFT_C 12.0f  // fixed softmax offset: exact (cancels in p/sum p)
#define LOG2E 1.4426950408889634f
#define SOFT_C2 17.312340490667560f  // SOFT_C * log2(e)

typedef unsigned short u16;
typedef __attribute__((ext_vector_type(8))) short bf16x8;  // K=32 A/B frag
typedef __attribute__((ext_vector_type(4))) short bf16x4;  // K=16 A/B frag
typedef __attribute__((ext_vector_type(4))) float f32x4;   // C/D frag

__device__ __forceinline__ float bf2f(u16 u) {
    return __uint_as_float(((unsigned)u) << 16);
}
__device__ __forceinline__ u16 f2bf(float f) {
    unsigned x = __float_as_uint(f);
    x += 0x7FFFu + ((x >> 16) & 1u);  // RNE
    return (u16)(x >> 16);
}
__device__ __forceinline__ f32x4 mfma_k32(bf16x8 a, bf16x8 b, f32x4 c) {
    return __builtin_amdgcn_mfma_f32_16x16x32_bf16(a, b, c, 0, 0, 0);
}
// padded-layout frag (attn K)
__device__ __forceinline__ bf16x8 ldfrag(const u16* base, int r0, int kc, int lane) {
    return *reinterpret_cast<const bf16x8*>(base + (r0 + (lane & 15)) * ST + kc +
                                            ((lane >> 4) << 3));
}
// linear-layout frag (GEMMs, stride 64 u16 — required by global_load_lds DMA)
__device__ __forceinline__ bf16x8 ldfragL(const u16* base, int r0, int kc, int lane) {
    return *reinterpret_cast<const bf16x8*>(base + ((r0 + (lane & 15)) << 6) + kc +
                                            ((lane >> 4) << 3));
}
__device__ __forceinline__ bf16x4 pack4(float a, float b, float c, float d) {
    union { bf16x4 v; __hip_bfloat162 h[2]; } u;
    u.h[0] = __float22bfloat162_rn(make_float2(a, b));
    u.h[1] = __float22bfloat162_rn(make_float2(c, d));
    return u.v;
}
// async global->LDS DMA, 16B/lane; LDS dst = wave-uniform base + lane*16
__device__ __forceinline__ void gl_lds16(const u16* g, u16* l) {
    __builtin_amdgcn_global_load_lds(
        (const __attribute__((address_space(1))) void*)g,
        (__attribute__((address_space(3))) void*)l, 16, 0, 0);
}
// stage ROWSx64 tile (row stride ld) into LINEAR LDS via DMA; 256 threads
template <int ROWS>
__device__ __forceinline__ void stage_dma(const u16* __restrict__ src, int ld,
                                          u16* dst, int lane, int w) {
#pragma unroll
    for (int c = 0; c < ROWS / 32; ++c) {
        int rbase = (w * (ROWS / 32) + c) * 8;
        const u16* g = src + (size_t)(rbase + (lane >> 3)) * ld + ((lane & 7) << 3);
        gl_lds16(g, dst + (rbase << 6));
    }
}

// ---------------------------------------------------------------------------
// dtype detector (+ init mask-nonzero flag to 0)
__global__ void detect_kernel(const u16* __restrict__ y, int* flag, int* mnz) {
    __shared__ int cnt;
    if (threadIdx.x == 0) cnt = 0;
    __syncthreads();
    int local = 0;
    for (int i = threadIdx.x; i < 8192; i += 256) {
        u16 u = y[i];
        int e = (u >> 7) & 0xFF;
        if (u == 0 || (e >= 96 && e < 160)) local++;
    }
    atomicAdd(&cnt, local);
    __syncthreads();
    if (threadIdx.x == 0) {
        *flag = (cnt > 7372) ? 1 : 0;
        *mnz = 0;
    }
}

// mask nonzero scan (bitwise OR of raw words — dtype-independent for zero)
__global__ __launch_bounds__(256) void scan_kernel(const void* __restrict__ msrc,
                                                   const int* __restrict__ flag,
                                                   int* __restrict__ mnz) {
    size_t n4 = (size_t)NN * NN / 8;
    if (!*flag) n4 *= 2;
    const uint4* p = (const uint4*)msrc;
    unsigned acc = 0;
    for (size_t i = (size_t)blockIdx.x * 256 + threadIdx.x; i < n4; i += 256 * 256) {
        uint4 v = p[i];
        acc |= v.x | v.y | v.z | v.w;
    }
    if (acc) atomicOr(mnz, 1);
}

// ---------------------------------------------------------------------------
// fused prepass: grid (256, 1, 6), block 256.
// z=0: convert y; z=1..3: convert+transpose weights ([KH][PD][DD]->
// [KH][DD][PD], LamY prescaled 0.125); z=4: ThY rearrange ([KH][QD][DD]->
// [QD][KH*DD]); z=5: mask convert+prescale (skipped when mask==0).
__global__ __launch_bounds__(256) void prep_kernel(
    const void* __restrict__ ysrc, const void* __restrict__ msrc,
    const void* __restrict__ s0, const void* __restrict__ s1,
    const void* __restrict__ s2, const void* __restrict__ s3,
    u16* __restrict__ ycan, u16* __restrict__ LamXt, u16* __restrict__ LamYt,
    u16* __restrict__ ThXt, u16* __restrict__ ThYr, u16* __restrict__ maskc,
    const int* __restrict__ flag, const int* __restrict__ mnz) {
    int z = blockIdx.z, bx = blockIdx.x, tid = threadIdx.x;
    int isbf = *flag;
    if (z == 0) {  // convert y'
        int n = BN * PD;
        for (int i = (bx * 256 + tid) * 4; i < n; i += 256 * 256 * 4) {
            if (isbf) {
                *reinterpret_cast<uint2*>(ycan + i) =
                    *reinterpret_cast<const uint2*>((const u16*)ysrc + i);
            } else {
                float4 f = *reinterpret_cast<const float4*>((const float*)ysrc + i);
                u16 t[4] = {f2bf(f.x), f2bf(f.y), f2bf(f.z), f2bf(f.w)};
                *reinterpret_cast<uint2*>(ycan + i) = *reinterpret_cast<uint2*>(t);
            }
        }
    } else if (z <= 3) {  // weight transpose
        const void* src = (z == 1) ? s0 : (z == 2) ? s1 : s2;
        u16* dst = (z == 1) ? LamXt : (z == 2) ? LamYt : ThXt;
        float scale = (z == 2) ? 0.125f : 1.0f;
        int k = bx >> 4, p0 = (bx & 15) * 64;
        __shared__ float T[64][65];
        const u16* s16 = (const u16*)src + ((size_t)k * PD + p0) * DD;
        const float* s32 = (const float*)src + ((size_t)k * PD + p0) * DD;
#pragma unroll
        for (int it = 0; it < 2; ++it) {
            int chunk = it * 256 + tid;
            int row = chunk >> 3, c8 = (chunk & 7) << 3;
            float f[8];
            if (isbf) {
                uint4 v = *reinterpret_cast<const uint4*>(s16 + row * DD + c8);
                u16 t[8];
                *reinterpret_cast<uint4*>(t) = v;
#pragma unroll
                for (int e = 0; e < 8; ++e) f[e] = bf2f(t[e]);
            } else {
                float4 a = *reinterpret_cast<const float4*>(s32 + row * DD + c8);
                float4 b = *reinterpret_cast<const float4*>(s32 + row * DD + c8 + 4);
                f[0] = a.x; f[1] = a.y; f[2] = a.z; f[3] = a.w;
                f[4] = b.x; f[5] = b.y; f[6] = b.z; f[7] = b.w;
            }
#pragma unroll
            for (int e = 0; e < 8; ++e) T[row][c8 + e] = f[e] * scale;
        }
        __syncthreads();
        u16* drow = dst + (size_t)k * DD * PD + p0;
#pragma unroll
        for (int it = 0; it < 2; ++it) {
            int chunk = it * 256 + tid;
            int d = chunk >> 3, c8 = (chunk & 7) << 3;
            u16 t[8];
#pragma unroll
            for (int e = 0; e < 8; ++e) t[e] = f2bf(T[c8 + e][d]);
            *reinterpret_cast<uint4*>(drow + (size_t)d * PD + c8) =
                *reinterpret_cast<uint4*>(t);
        }
    } else if (z == 4) {  // ThY rearrange
        int k = bx >> 4, q0 = (bx & 15) * 64;
#pragma unroll
        for (int it = 0; it < 2; ++it) {
            int chunk = it * 256 + tid;
            int row = chunk >> 3, c8 = (chunk & 7) << 3;
            size_t si = ((size_t)k * QD + q0 + row) * DD + c8;
            u16 t[8];
            if (isbf) {
                *reinterpret_cast<uint4*>(t) =
                    *reinterpret_cast<const uint4*>((const u16*)s3 + si);
            } else {
                float4 a = *reinterpret_cast<const float4*>((const float*)s3 + si);
                float4 b = *reinterpret_cast<const float4*>((const float*)s3 + si + 4);
                t[0] = f2bf(a.x); t[1] = f2bf(a.y); t[2] = f2bf(a.z); t[3] = f2bf(a.w);
                t[4] = f2bf(b.x); t[5] = f2bf(b.y); t[6] = f2bf(b.z); t[7] = f2bf(b.w);
            }
            *reinterpret_cast<uint4*>(ThYr + (size_t)(q0 + row) * (KH * DD) +
                                      k * DD + c8) = *reinterpret_cast<uint4*>(t);
        }
    } else {  // z == 5: mask convert + prescale (only if mask nonzero)
        if (*mnz == 0) return;
        size_t n8 = (size_t)NN * NN / 8;
        for (size_t c = (size_t)bx * 256 + tid; c < n8; c += 256 * 256) {
            size_t i = c * 8;
            float f[8];
            if (isbf) {
                uint4 v = *reinterpret_cast<const uint4*>((const u16*)msrc + i);
                u16 t[8];
                *reinterpret_cast<uint4*>(t) = v;
#pragma unroll
                for (int e = 0; e < 8; ++e) f[e] = bf2f(t[e]);
            } else {
                float4 a = *reinterpret_cast<const float4*>((const float*)msrc + i);
                float4 b = *reinterpret_cast<const float4*>((const float*)msrc + i + 4);
                f[0] = a.x; f[1] = a.y; f[2] = a.z; f[3] = a.w;
                f[4] = b.x; f[5] = b.y; f[6] = b.z; f[7] = b.w;
            }
            u16 t[8];
#pragma unroll
            for (int e = 0; e < 8; ++e) t[e] = f2bf(f[e] * 0.125f);
            *reinterpret_cast<uint4*>(maskc + i) = *reinterpret_cast<uint4*>(t);
        }
    }
}

// ---------------------------------------------------------------------------
// Kernel 1: projections GEMM [BN x PD] x [PD x 3072], DMA staging, linear LDS,
// LDS-staged full-line epilogue. grid (BN/128, 3072/128), block 256.
// V output (s==2) is stored FRAGMENT-MAJOR: per (head, 32-token block c,
// d-group dg) a 1KB block holding the 16x16x32 PV A-fragment in lane order
// (lane*16B), with the within-32 key permutation p = quad*8 + h*4 + r for
// token w = h*16 + quad*4 + r. attn reads each fragment as ONE coalesced
// 16B/lane load at base + lane*8 (u16).
__global__ __launch_bounds__(256, 3) void proj_gemm(
    const u16* __restrict__ A,   // ycan [BN][PD]
    const u16* __restrict__ Bm,  // Wcat [3072][PD]
    u16* __restrict__ Xk, u16* __restrict__ Yk, u16* __restrict__ Vtg) {
    int tid = threadIdx.x, lane = tid & 63, w = tid >> 6;
    int mhalf = w & 1, nhalf = w >> 1;
    int m0 = blockIdx.x * 128, n0 = blockIdx.y * 128;
    __shared__ u16 As[128 * 64];
    __shared__ u16 Bs[128 * 64];
    f32x4 acc[4][4] = {};

    for (int kk = 0; kk < PD; kk += 64) {
        __syncthreads();
        stage_dma<128>(A + (size_t)m0 * PD + kk, PD, As, lane, w);
        stage_dma<128>(Bm + (size_t)n0 * PD + kk, PD, Bs, lane, w);
        __syncthreads();
#pragma unroll
        for (int kc = 0; kc < 64; kc += 32) {
            bf16x8 af[4], bf[4];
#pragma unroll
            for (int i = 0; i < 4; ++i) af[i] = ldfragL(As, mhalf * 64 + i * 16, kc, lane);
#pragma unroll
            for (int j = 0; j < 4; ++j) bf[j] = ldfragL(Bs, nhalf * 64 + j * 16, kc, lane);
#pragma unroll
            for (int i = 0; i < 4; ++i)
#pragma unroll
                for (int j = 0; j < 4; ++j) acc[i][j] = mfma_k32(af[i], bf[j], acc[i][j]);
        }
    }
    int s = n0 >> 10;  // tile never crosses the 1024 boundary
    int quad = lane >> 4, col = lane & 15;
    u16* stg = nhalf ? Bs : As;  // this wave-pair's 128x64 output half
    __syncthreads();             // K-loop LDS reads complete
    if (s == 2) {
        // stage fragment-major: local idx = (cLoc*4 + jj)*512 + quad*128 +
        // col*8 + (i&1)*4 + r, where cLoc = mhalf*2 + (i>>1). Global copy is
        // then LINEAR (head_base + m0*64 + idx).
#pragma unroll
        for (int i = 0; i < 4; ++i)
#pragma unroll
            for (int j = 0; j < 4; ++j)
                *reinterpret_cast<bf16x4*>(stg + ((mhalf * 2 + (i >> 1)) * 4 + j) * 512 +
                                           quad * 128 + col * 8 + (i & 1) * 4) =
                    pack4(acc[i][j][0], acc[i][j][1], acc[i][j][2], acc[i][j][3]);
    } else {
        // stage as [tok 128][d 64] (linear = global layout)
#pragma unroll
        for (int i = 0; i < 4; ++i)
#pragma unroll
            for (int j = 0; j < 4; ++j)
#pragma unroll
                for (int reg = 0; reg < 4; ++reg)
                    stg[(mhalf * 64 + i * 16 + quad * 4 + reg) * 64 + j * 16 + col] =
                        f2bf(acc[i][j][reg]);
    }
    __syncthreads();
#pragma unroll
    for (int h = 0; h < 2; ++h) {
        int kh = ((n0 + h * 64) >> 6) & 15;
        const u16* src = h ? Bs : As;
        if (s == 2) {
            u16* vb = Vtg + (size_t)kh * DD * BN + (size_t)m0 * 64;
#pragma unroll
            for (int it = 0; it < 4; ++it) {
                int chunk = it * 256 + tid;  // 1024 uint4, fully linear
                *reinterpret_cast<uint4*>(vb + chunk * 8) =
                    *reinterpret_cast<const uint4*>(src + chunk * 8);
            }
        } else {
            u16* ob = (s == 0 ? Xk : Yk) + (size_t)kh * BN * DD + (size_t)m0 * DD;
#pragma unroll
            for (int it = 0; it < 4; ++it) {
                int chunk = it * 256 + tid;
                *reinterpret_cast<uint4*>(ob + chunk * 8) =
                    *reinterpret_cast<const uint4*>(src + chunk * 8);
            }
        }
    }
}

// ---------------------------------------------------------------------------
// Kernel 2a: flash attention v5b — SPLIT-K. Grid 1024 (XCD-swizzled): each
// block computes HALF the key range (16 tiles) for a 128-q tile, writing
// unnormalized f32 O-partials + l-partials; merge_kernel combines.
// __launch_bounds__(512, 4): R4's (512,8) forced a 32-VGPR budget and the
// kernel spilled (FETCH 0.5GB/WRITE 0.86GB of scratch). At 64 VGPR (R3's
// natural allocation for this body) the HW allows 32 waves/CU, so the
// 1024-block grid yields 4 independent 8-wave barrier groups per CU —
// the occupancy the split was designed for, without the register squeeze.
// K: LDS triple buffer (reg-staged, padded). V: global frag-major via L1.
__global__ __launch_bounds__(512, 4) void attn_split(
    const u16* __restrict__ Xk,     // keys    [KH][BN][DD]
    const u16* __restrict__ Yk,     // queries [KH][BN][DD] prescaled /8
    const u16* __restrict__ Vtg,    // V frag-major [KH][BN/32][4][64*8]
    const u16* __restrict__ maskc,  // [NN][NN] bf16 prescaled /8
    const int* __restrict__ mnz,
    float* __restrict__ Opart,      // [2][KH][BB][NN][DD] f32
    float* __restrict__ Lp) {       // [2][KH][BB][NN] f32
    int tid = threadIdx.x, lane = tid & 63, w = tid >> 6;  // w in [0,8)
    int quad = lane >> 4, col = lane & 15;
    // XCD swizzle: hw block H (XCD=H%8) -> work L; per XCD: 4 (k,b) combos,
    // all 16 q-tiles and both key-halves of each (shared K/V panels in L2).
    int H = blockIdx.x;
    int L = (H & 7) * 128 + (H >> 3);
    int half = L & 1;
    int q0 = ((L >> 1) & 15) * 128, k = (L >> 5) & 15, b = L >> 9;
    int t0 = half * 16;
    const u16* Qp = Yk + ((size_t)k * BN + b * NN + q0) * DD;
    const u16* Kp = Xk + ((size_t)k * BN + b * NN) * DD;
    const u16* Vh = Vtg + (size_t)k * DD * BN + (size_t)b * NN * 64;
    __shared__ u16 Kb[3][64 * ST];  // K triple buffer (27.6 KB total)
    int mz = *mnz;

    // Q B-frags straight from global: element j = Q[q][quad*8 + j (+32)]
    const u16* qrow = Qp + (size_t)(w * 16 + col) * DD + (quad << 3);
    bf16x8 qf0 = *reinterpret_cast<const bf16x8*>(qrow);
    bf16x8 qf1 = *reinterpret_cast<const bf16x8*>(qrow + 32);

    // K staging slot: one uint4 per thread per tile (64x64 = 512*16B)
    int srow = tid >> 3, scol = (tid & 7) << 3;
    const u16* kgp = Kp + (size_t)srow * DD + scol;
    int soff = srow * ST + scol;

    // prologue: tile t0 -> buf0; tile t0+1 load in flight
    uint4 kr = *reinterpret_cast<const uint4*>(kgp + (size_t)t0 * 64 * DD);
    *reinterpret_cast<uint4*>(Kb[0] + soff) = kr;
    kr = *reinterpret_cast<const uint4*>(kgp + (size_t)(t0 + 1) * 64 * DD);
    __syncthreads();  // buf0 visible

    float lp = 0.0f;
    f32x4 oacc[4] = {};  // O^T[d][q] d-groups

    for (int tt = 0; tt < 16; ++tt) {
        int t = t0 + tt;
        int cur = tt % 3;
        if (tt < 15) {
            int nxt = (tt + 1) % 3;
            *reinterpret_cast<uint4*>(Kb[nxt] + soff) = kr;
            __syncthreads();  // buf[nxt] visible
        }
        const u16* Ks = Kb[cur];
        // V A-frags: coalesced 1KB loads (L1-resident after first wave)
        const u16* vt = Vh + t * 4096;
        bf16x8 av[2][4];
#pragma unroll
        for (int hlf = 0; hlf < 2; ++hlf)
#pragma unroll
            for (int dg = 0; dg < 4; ++dg)
                av[hlf][dg] = *reinterpret_cast<const bf16x8*>(
                    vt + hlf * 2048 + dg * 512 + lane * 8);
        // K reg prefetch 2 tiles ahead
        if (tt < 14)
            kr = *reinterpret_cast<const uint4*>(kgp + (size_t)(t + 2) * 64 * DD);
        int m0 = t * 64;

        // S^T[key][q] = K Q^T (prescaled); exp inline per key-group
        bf16x4 pb4[4];
#pragma unroll
        for (int kg = 0; kg < 4; ++kg) {
            bf16x8 a0 = ldfrag(Ks, kg * 16, 0, lane);
            bf16x8 a1 = ldfrag(Ks, kg * 16, 32, lane);
            f32x4 s = {};
            s = mfma_k32(a0, qf0, s);
            s = mfma_k32(a1, qf1, s);
            if (mz) {
#pragma unroll
                for (int reg = 0; reg < 4; ++reg)
                    s[reg] += bf2f(
                        maskc[(size_t)(m0 + kg * 16 + quad * 4 + reg) * NN + q0 +
                              w * 16 + col]);
            }
            float p0 = exp2f(fmaf(s[0], LOG2E, -SOFT_C2));
            float p1 = exp2f(fmaf(s[1], LOG2E, -SOFT_C2));
            float p2 = exp2f(fmaf(s[2], LOG2E, -SOFT_C2));
            float p3 = exp2f(fmaf(s[3], LOG2E, -SOFT_C2));
            lp += (p0 + p1) + (p2 + p3);
            pb4[kg] = pack4(p0, p1, p2, p3);
        }
        // O^T += V^T P^T; A (frag-major V) and B (concat P) share the key
        // perm: slot (quad,j) <-> key = hlf*32 + (j>=4)*16 + quad*4 + (j&3)
#pragma unroll
        for (int hlf = 0; hlf < 2; ++hlf) {
            bf16x8 pb8 = __builtin_shufflevector(pb4[hlf * 2], pb4[hlf * 2 + 1],
                                                 0, 1, 2, 3, 4, 5, 6, 7);
#pragma unroll
            for (int dg = 0; dg < 4; ++dg)
                oacc[dg] = mfma_k32(av[hlf][dg], pb8, oacc[dg]);
        }
    }

    // epilogue: write unnormalized f32 partials (coalesced 16B stores)
    float l = lp;
    l += __shfl_xor(l, 16);
    l += __shfl_xor(l, 32);
    size_t qi = ((size_t)k * BB + b) * NN + q0 + w * 16 + col;
    if (quad == 0) Lp[(size_t)half * KH * BB * NN + qi] = l;
    float* Oph = Opart + (size_t)half * KH * BB * NN * 64 + qi * 64;
#pragma unroll
    for (int dg = 0; dg < 4; ++dg)
        *reinterpret_cast<f32x4*>(Oph + dg * 16 + quad * 4) = oacc[dg];
}

// merge: O[row][k*64+d] = (O0+O1)/(l0+l1), bf16. grid 2048 x 256.
__global__ __launch_bounds__(256) void merge_kernel(
    const float* __restrict__ Opart, const float* __restrict__ Lp,
    u16* __restrict__ O) {
    int flat = blockIdx.x * 256 + threadIdx.x;  // 524288 chunks of 8 u16
    int row = flat >> 7;
    int col8 = (flat & 127) << 3;
    int k = col8 >> 6, d0 = col8 & 63;
    int b = row >> 11, q = row & (NN - 1);
    size_t qi = ((size_t)k * BB + b) * NN + q;
    const size_t HO = (size_t)KH * BB * NN * 64;
    size_t pi = qi * 64 + d0;
    float4 a0 = *reinterpret_cast<const float4*>(Opart + pi);
    float4 a1 = *reinterpret_cast<const float4*>(Opart + pi + 4);
    float4 b0 = *reinterpret_cast<const float4*>(Opart + HO + pi);
    float4 b1 = *reinterpret_cast<const float4*>(Opart + HO + pi + 4);
    float inv = 1.0f / (Lp[qi] + Lp[KH * BB * NN + qi]);
    u16 t[8];
    t[0] = f2bf((a0.x + b0.x) * inv);
    t[1] = f2bf((a0.y + b0.y) * inv);
    t[2] = f2bf((a0.z + b0.z) * inv);
    t[3] = f2bf((a0.w + b0.w) * inv);
    t[4] = f2bf((a1.x + b1.x) * inv);
    t[5] = f2bf((a1.y + b1.y) * inv);
    t[6] = f2bf((a1.z + b1.z) * inv);
    t[7] = f2bf((a1.w + b1.w) * inv);
    *reinterpret_cast<uint4*>(O + (size_t)row * (KH * DD) + col8) =
        *reinterpret_cast<uint4*>(t);
}

// ---------------------------------------------------------------------------
// Kernel 2b: fallback full attention (R3 structure) when workspace too small
// for split-K partials. grid 512, block 512.
__global__ __launch_bounds__(512, 4) void attn_full(
    const u16* __restrict__ Xk, const u16* __restrict__ Yk,
    const u16* __restrict__ Vtg, const u16* __restrict__ maskc,
    const int* __restrict__ mnz, u16* __restrict__ O) {
    int tid = threadIdx.x, lane = tid & 63, w = tid >> 6;
    int quad = lane >> 4, col = lane & 15;
    int H = blockIdx.x;
    int L = (H & 7) * 64 + (H >> 3);
    int q0 = (L & 15) * 128, k = (L >> 4) & 15, b = L >> 8;
    const u16* Qp = Yk + ((size_t)k * BN + b * NN + q0) * DD;
    const u16* Kp = Xk + ((size_t)k * BN + b * NN) * DD;
    const u16* Vh = Vtg + (size_t)k * DD * BN + (size_t)b * NN * 64;
    __shared__ u16 Kb[3][64 * ST];
    __shared__ u16 Ost[128 * ST];
    int mz = *mnz;

    const u16* qrow = Qp + (size_t)(w * 16 + col) * DD + (quad << 3);
    bf16x8 qf0 = *reinterpret_cast<const bf16x8*>(qrow);
    bf16x8 qf1 = *reinterpret_cast<const bf16x8*>(qrow + 32);

    int srow = tid >> 3, scol = (tid & 7) << 3;
    const u16* kgp = Kp + (size_t)srow * DD + scol;
    int soff = srow * ST + scol;

    uint4 kr = *reinterpret_cast<const uint4*>(kgp);
    *reinterpret_cast<uint4*>(Kb[0] + soff) = kr;
    kr = *reinterpret_cast<const uint4*>(kgp + (size_t)64 * DD);
    __syncthreads();

    float lp = 0.0f;
    f32x4 oacc[4] = {};

    for (int t = 0; t < 32; ++t) {
        int cur = t % 3;
        if (t < 31) {
            int nxt = (t + 1) % 3;
            *reinterpret_cast<uint4*>(Kb[nxt] + soff) = kr;
            __syncthreads();
        }
        const u16* Ks = Kb[cur];
        const u16* vt = Vh + t * 4096;
        bf16x8 av[2][4];
#pragma unroll
        for (int hlf = 0; hlf < 2; ++hlf)
#pragma unroll
            for (int dg = 0; dg < 4; ++dg)
                av[hlf][dg] = *reinterpret_cast<const bf16x8*>(
                    vt + hlf * 2048 + dg * 512 + lane * 8);
        if (t < 30) kr = *reinterpret_cast<const uint4*>(kgp + (size_t)(t + 2) * 64 * DD);
        int m0 = t * 64;

        bf16x4 pb4[4];
#pragma unroll
        for (int kg = 0; kg < 4; ++kg) {
            bf16x8 a0 = ldfrag(Ks, kg * 16, 0, lane);
            bf16x8 a1 = ldfrag(Ks, kg * 16, 32, lane);
            f32x4 s = {};
            s = mfma_k32(a0, qf0, s);
            s = mfma_k32(a1, qf1, s);
            if (mz) {
#pragma unroll
                for (int reg = 0; reg < 4; ++reg)
                    s[reg] += bf2f(
                        maskc[(size_t)(m0 + kg * 16 + quad * 4 + reg) * NN + q0 +
                              w * 16 + col]);
            }
            float p0 = exp2f(fmaf(s[0], LOG2E, -SOFT_C2));
            float p1 = exp2f(fmaf(s[1], LOG2E, -SOFT_C2));
            float p2 = exp2f(fmaf(s[2], LOG2E, -SOFT_C2));
            float p3 = exp2f(fmaf(s[3], LOG2E, -SOFT_C2));
            lp += (p0 + p1) + (p2 + p3);
            pb4[kg] = pack4(p0, p1, p2, p3);
        }
#pragma unroll
        for (int hlf = 0; hlf < 2; ++hlf) {
            bf16x8 pb8 = __builtin_shufflevector(pb4[hlf * 2], pb4[hlf * 2 + 1],
                                                 0, 1, 2, 3, 4, 5, 6, 7);
#pragma unroll
            for (int dg = 0; dg < 4; ++dg)
                oacc[dg] = mfma_k32(av[hlf][dg], pb8, oacc[dg]);
        }
    }

    float l = lp;
    l += __shfl_xor(l, 16);
    l += __shfl_xor(l, 32);
    float inv = 1.0f / l;
    int q = w * 16 + col;
#pragma unroll
    for (int dg = 0; dg < 4; ++dg)
        *reinterpret_cast<bf16x4*>(Ost + q * ST + dg * 16 + quad * 4) =
            pack4(oacc[dg][0] * inv, oacc[dg][1] * inv, oacc[dg][2] * inv,
                  oacc[dg][3] * inv);
    __syncthreads();
#pragma unroll
    for (int it = 0; it < 2; ++it) {
        int chunk = it * 512 + tid;
        int row = chunk >> 3, c8 = (chunk & 7) << 3;
        *reinterpret_cast<uint4*>(O + (size_t)(b * NN + q0 + row) * (KH * DD) +
                                  k * DD + c8) =
            *reinterpret_cast<const uint4*>(Ost + row * ST + c8);
    }
}

// ---------------------------------------------------------------------------
// Kernel 3: output projection GEMM [BN x 1024] x [1024 x QD], DMA staging,
// fp32 epilogue staged through LDS for full-line writes.
// grid (BN/128, QD/128), block 256.
__global__ __launch_bounds__(256, 3) void out_gemm(
    const u16* __restrict__ A,   // Ob [BN][KH*DD]
    const u16* __restrict__ Bm,  // ThYr [QD][KH*DD]
    const int* __restrict__ flag,
    void* __restrict__ outv) {
    int tid = threadIdx.x, lane = tid & 63, w = tid >> 6;
    int mhalf = w & 1, nhalf = w >> 1;
    int m0 = blockIdx.x * 128, n0 = blockIdx.y * 128;
    __shared__ u16 S[2][128 * 64];  // As | Bs; reused as fp32 stage (32KB)
    u16* As = S[0];
    u16* Bs = S[1];
    f32x4 acc[4][4] = {};

    for (int kk = 0; kk < KH * DD; kk += 64) {
        __syncthreads();
        stage_dma<128>(A + (size_t)m0 * (KH * DD) + kk, KH * DD, As, lane, w);
        stage_dma<128>(Bm + (size_t)n0 * (KH * DD) + kk, KH * DD, Bs, lane, w);
        __syncthreads();
#pragma unroll
        for (int kc = 0; kc < 64; kc += 32) {
            bf16x8 af[4], bf[4];
#pragma unroll
            for (int i = 0; i < 4; ++i) af[i] = ldfragL(As, mhalf * 64 + i * 16, kc, lane);
#pragma unroll
            for (int j = 0; j < 4; ++j) bf[j] = ldfragL(Bs, nhalf * 64 + j * 16, kc, lane);
#pragma unroll
            for (int i = 0; i < 4; ++i)
#pragma unroll
                for (int j = 0; j < 4; ++j) acc[i][j] = mfma_k32(af[i], bf[j], acc[i][j]);
        }
    }
    int isbf = *flag;
    int quad = lane >> 4, col = lane & 15;
    if (isbf) {
#pragma unroll
        for (int i = 0; i < 4; ++i)
#pragma unroll
            for (int j = 0; j < 4; ++j)
#pragma unroll
                for (int reg = 0; reg < 4; ++reg) {
                    size_t row = m0 + mhalf * 64 + i * 16 + quad * 4 + reg;
                    int c = n0 + nhalf * 64 + j * 16 + col;
                    ((u16*)outv)[row * QD + c] = f2bf(acc[i][j][reg]);
                }
    } else {
        float* Sf = (float*)&S[0][0];  // 64 rows x 128 f32 (32KB)
#pragma unroll
        for (int h = 0; h < 2; ++h) {
            __syncthreads();  // K-loop frag reads / previous copy done
            if (mhalf == h) {
#pragma unroll
                for (int i = 0; i < 4; ++i)
#pragma unroll
                    for (int j = 0; j < 4; ++j)
#pragma unroll
                        for (int reg = 0; reg < 4; ++reg)
                            Sf[(i * 16 + quad * 4 + reg) * 128 + nhalf * 64 +
                               j * 16 + col] = acc[i][j][reg];
            }
            __syncthreads();
            float* orow = (float*)outv + (size_t)(m0 + h * 64) * QD + n0;
#pragma unroll
            for (int it = 0; it < 8; ++it) {
                int chunk = it * 256 + tid;  // 2048 chunks of 4 f32
                int row = chunk >> 5, c4 = (chunk & 31) * 4;
                *reinterpret_cast<float4*>(orow + (size_t)row * QD + c4) =
                    *reinterpret_cast<const float4*>(Sf + row * 128 + c4);
            }
        }
    }
}

// ---------------------------------------------------------------------------
extern "C" void kernel_launch(void* const* d_in, const int* in_sizes, int n_in,
                              void* d_out, int out_size, void* d_ws, size_t ws_size,
                              hipStream_t stream) {
    // ws: flag|mnz 64B; ycan 8.39M (-> Ob after proj); Wcat 3x2.1M; ThYr 2.1M;
    // Xk/Yk/Vtg 8.39M each; maskc 8.39M; Opart 33.6M; Lp 0.52M  => ~84.4 MB
    char* wsb = (char*)d_ws;
    int* flag = (int*)wsb;
    int* mnz = (int*)(wsb + 16);
    u16* ycan = (u16*)(wsb + 64);
    const size_t NYP = (size_t)BN * PD;
    const size_t NW = (size_t)KH * PD * DD;
    const size_t OSZ = (size_t)BN * KH * DD;
    u16* Wcat = ycan + NYP;  // LamXt | LamYt/8 | ThXt contiguous
    u16* ThYr = Wcat + 3 * NW;
    u16* Xk = ThYr + NW;
    u16* Yk = Xk + OSZ;
    u16* Vtg = Yk + OSZ;
    u16* maskc = Vtg + OSZ;
    u16* Ob = ycan;  // aliases ycan (dead after proj_gemm)
    float* Opart = (float*)(maskc + (size_t)NN * NN);
    float* Lp = Opart + 2 * (size_t)KH * BB * NN * 64;
    size_t need = (size_t)((char*)(Lp + 2 * (size_t)KH * BB * NN) - wsb);
    bool split = ws_size >= need;

    detect_kernel<<<1, 256, 0, stream>>>((const u16*)d_in[0], flag, mnz);
    scan_kernel<<<256, 256, 0, stream>>>(d_in[1], flag, mnz);
    prep_kernel<<<dim3(256, 1, 6), 256, 0, stream>>>(
        d_in[0], d_in[1], d_in[2], d_in[3], d_in[4], d_in[5], ycan, Wcat,
        Wcat + NW, Wcat + 2 * NW, ThYr, maskc, flag, mnz);
    proj_gemm<<<dim3(BN / 128, 3072 / 128), 256, 0, stream>>>(ycan, Wcat, Xk, Yk, Vtg);
    if (split) {
        attn_split<<<1024, 512, 0, stream>>>(Xk, Yk, Vtg, maskc, mnz, Opart, Lp);
        merge_kernel<<<2048, 256, 0, stream>>>(Opart, Lp, Ob);
    } else {
        attn_full<<<512, 512, 0, stream>>>(Xk, Yk, Vtg, maskc, mnz, Ob);
    }
    out_gemm<<<dim3(BN / 128, QD / 128), 256, 0, stream>>>(Ob, ThYr, flag, d_out);
}

// Round 6
// 238.129 us; speedup vs baseline: 2.1084x; 1.0338x over previous
//
#include <hip/hip_runtime.h>
#include <hip/hip_bf16.h>

// Bilinear multi-head self-attention, MI355X
#define KH 16    // heads
#define PD 1024  // value-in dim
#define QD 1024  // out dim
#define DD 64    // head dim
#define BB 2     // batch
#define NN 2048  // seq len
#define BN 4096  // BB*NN rows
#define ST 72    // padded LDS row stride (u16) for attn
#define SOFT_C 12.0f  // fixed softmax offset: exact (cancels in p/sum p)
#define LOG2E 1.4426950408889634f
#define SOFT_C2 17.312340490667560f  // SOFT_C * log2(e)

typedef unsigned short u16;
typedef __attribute__((ext_vector_type(8))) short bf16x8;  // K=32 A/B frag
typedef __attribute__((ext_vector_type(4))) short bf16x4;  // K=16 A/B frag
typedef __attribute__((ext_vector_type(4))) float f32x4;   // C/D frag

__device__ __forceinline__ float bf2f(u16 u) {
    return __uint_as_float(((unsigned)u) << 16);
}
__device__ __forceinline__ u16 f2bf(float f) {
    unsigned x = __float_as_uint(f);
    x += 0x7FFFu + ((x >> 16) & 1u);  // RNE
    return (u16)(x >> 16);
}
__device__ __forceinline__ f32x4 mfma_k32(bf16x8 a, bf16x8 b, f32x4 c) {
    return __builtin_amdgcn_mfma_f32_16x16x32_bf16(a, b, c, 0, 0, 0);
}
// padded-layout frag (attn K)
__device__ __forceinline__ bf16x8 ldfrag(const u16* base, int r0, int kc, int lane) {
    return *reinterpret_cast<const bf16x8*>(base + (r0 + (lane & 15)) * ST + kc +
                                            ((lane >> 4) << 3));
}
// linear-layout frag (GEMMs, stride 64 u16 — required by global_load_lds DMA)
__device__ __forceinline__ bf16x8 ldfragL(const u16* base, int r0, int kc, int lane) {
    return *reinterpret_cast<const bf16x8*>(base + ((r0 + (lane & 15)) << 6) + kc +
                                            ((lane >> 4) << 3));
}
__device__ __forceinline__ bf16x4 pack4(float a, float b, float c, float d) {
    union { bf16x4 v; __hip_bfloat162 h[2]; } u;
    u.h[0] = __float22bfloat162_rn(make_float2(a, b));
    u.h[1] = __float22bfloat162_rn(make_float2(c, d));
    return u.v;
}
// async global->LDS DMA, 16B/lane; LDS dst = wave-uniform base + lane*16
__device__ __forceinline__ void gl_lds16(const u16* g, u16* l) {
    __builtin_amdgcn_global_load_lds(
        (const __attribute__((address_space(1))) void*)g,
        (__attribute__((address_space(3))) void*)l, 16, 0, 0);
}
// stage ROWSx64 tile (row stride ld) into LINEAR LDS via DMA; 256 threads
template <int ROWS>
__device__ __forceinline__ void stage_dma(const u16* __restrict__ src, int ld,
                                          u16* dst, int lane, int w) {
#pragma unroll
    for (int c = 0; c < ROWS / 32; ++c) {
        int rbase = (w * (ROWS / 32) + c) * 8;
        const u16* g = src + (size_t)(rbase + (lane >> 3)) * ld + ((lane & 7) << 3);
        gl_lds16(g, dst + (rbase << 6));
    }
}

// ---------------------------------------------------------------------------
// dtype detector (+ init mask-nonzero flag to 0)
__global__ void detect_kernel(const u16* __restrict__ y, int* flag, int* mnz) {
    __shared__ int cnt;
    if (threadIdx.x == 0) cnt = 0;
    __syncthreads();
    int local = 0;
    for (int i = threadIdx.x; i < 8192; i += 256) {
        u16 u = y[i];
        int e = (u >> 7) & 0xFF;
        if (u == 0 || (e >= 96 && e < 160)) local++;
    }
    atomicAdd(&cnt, local);
    __syncthreads();
    if (threadIdx.x == 0) {
        *flag = (cnt > 7372) ? 1 : 0;
        *mnz = 0;
    }
}

// mask nonzero scan (bitwise OR of raw words — dtype-independent for zero)
__global__ __launch_bounds__(256) void scan_kernel(const void* __restrict__ msrc,
                                                   const int* __restrict__ flag,
                                                   int* __restrict__ mnz) {
    size_t n4 = (size_t)NN * NN / 8;
    if (!*flag) n4 *= 2;
    const uint4* p = (const uint4*)msrc;
    unsigned acc = 0;
    for (size_t i = (size_t)blockIdx.x * 256 + threadIdx.x; i < n4; i += 256 * 256) {
        uint4 v = p[i];
        acc |= v.x | v.y | v.z | v.w;
    }
    if (acc) atomicOr(mnz, 1);
}

// ---------------------------------------------------------------------------
// fused prepass: grid (256, 1, 6), block 256.
// z=0: convert y; z=1..3: convert+transpose weights ([KH][PD][DD]->
// [KH][DD][PD], LamY prescaled 0.125); z=4: ThY rearrange ([KH][QD][DD]->
// [QD][KH*DD]); z=5: mask convert+prescale (skipped when mask==0).
__global__ __launch_bounds__(256) void prep_kernel(
    const void* __restrict__ ysrc, const void* __restrict__ msrc,
    const void* __restrict__ s0, const void* __restrict__ s1,
    const void* __restrict__ s2, const void* __restrict__ s3,
    u16* __restrict__ ycan, u16* __restrict__ LamXt, u16* __restrict__ LamYt,
    u16* __restrict__ ThXt, u16* __restrict__ ThYr, u16* __restrict__ maskc,
    const int* __restrict__ flag, const int* __restrict__ mnz) {
    int z = blockIdx.z, bx = blockIdx.x, tid = threadIdx.x;
    int isbf = *flag;
    if (z == 0) {  // convert y'
        int n = BN * PD;
        for (int i = (bx * 256 + tid) * 4; i < n; i += 256 * 256 * 4) {
            if (isbf) {
                *reinterpret_cast<uint2*>(ycan + i) =
                    *reinterpret_cast<const uint2*>((const u16*)ysrc + i);
            } else {
                float4 f = *reinterpret_cast<const float4*>((const float*)ysrc + i);
                u16 t[4] = {f2bf(f.x), f2bf(f.y), f2bf(f.z), f2bf(f.w)};
                *reinterpret_cast<uint2*>(ycan + i) = *reinterpret_cast<uint2*>(t);
            }
        }
    } else if (z <= 3) {  // weight transpose
        const void* src = (z == 1) ? s0 : (z == 2) ? s1 : s2;
        u16* dst = (z == 1) ? LamXt : (z == 2) ? LamYt : ThXt;
        float scale = (z == 2) ? 0.125f : 1.0f;
        int k = bx >> 4, p0 = (bx & 15) * 64;
        __shared__ float T[64][65];
        const u16* s16 = (const u16*)src + ((size_t)k * PD + p0) * DD;
        const float* s32 = (const float*)src + ((size_t)k * PD + p0) * DD;
#pragma unroll
        for (int it = 0; it < 2; ++it) {
            int chunk = it * 256 + tid;
            int row = chunk >> 3, c8 = (chunk & 7) << 3;
            float f[8];
            if (isbf) {
                uint4 v = *reinterpret_cast<const uint4*>(s16 + row * DD + c8);
                u16 t[8];
                *reinterpret_cast<uint4*>(t) = v;
#pragma unroll
                for (int e = 0; e < 8; ++e) f[e] = bf2f(t[e]);
            } else {
                float4 a = *reinterpret_cast<const float4*>(s32 + row * DD + c8);
                float4 b = *reinterpret_cast<const float4*>(s32 + row * DD + c8 + 4);
                f[0] = a.x; f[1] = a.y; f[2] = a.z; f[3] = a.w;
                f[4] = b.x; f[5] = b.y; f[6] = b.z; f[7] = b.w;
            }
#pragma unroll
            for (int e = 0; e < 8; ++e) T[row][c8 + e] = f[e] * scale;
        }
        __syncthreads();
        u16* drow = dst + (size_t)k * DD * PD + p0;
#pragma unroll
        for (int it = 0; it < 2; ++it) {
            int chunk = it * 256 + tid;
            int d = chunk >> 3, c8 = (chunk & 7) << 3;
            u16 t[8];
#pragma unroll
            for (int e = 0; e < 8; ++e) t[e] = f2bf(T[c8 + e][d]);
            *reinterpret_cast<uint4*>(drow + (size_t)d * PD + c8) =
                *reinterpret_cast<uint4*>(t);
        }
    } else if (z == 4) {  // ThY rearrange
        int k = bx >> 4, q0 = (bx & 15) * 64;
#pragma unroll
        for (int it = 0; it < 2; ++it) {
            int chunk = it * 256 + tid;
            int row = chunk >> 3, c8 = (chunk & 7) << 3;
            size_t si = ((size_t)k * QD + q0 + row) * DD + c8;
            u16 t[8];
            if (isbf) {
                *reinterpret_cast<uint4*>(t) =
                    *reinterpret_cast<const uint4*>((const u16*)s3 + si);
            } else {
                float4 a = *reinterpret_cast<const float4*>((const float*)s3 + si);
                float4 b = *reinterpret_cast<const float4*>((const float*)s3 + si + 4);
                t[0] = f2bf(a.x); t[1] = f2bf(a.y); t[2] = f2bf(a.z); t[3] = f2bf(a.w);
                t[4] = f2bf(b.x); t[5] = f2bf(b.y); t[6] = f2bf(b.z); t[7] = f2bf(b.w);
            }
            *reinterpret_cast<uint4*>(ThYr + (size_t)(q0 + row) * (KH * DD) +
                                      k * DD + c8) = *reinterpret_cast<uint4*>(t);
        }
    } else {  // z == 5: mask convert + prescale (only if mask nonzero)
        if (*mnz == 0) return;
        size_t n8 = (size_t)NN * NN / 8;
        for (size_t c = (size_t)bx * 256 + tid; c < n8; c += 256 * 256) {
            size_t i = c * 8;
            float f[8];
            if (isbf) {
                uint4 v = *reinterpret_cast<const uint4*>((const u16*)msrc + i);
                u16 t[8];
                *reinterpret_cast<uint4*>(t) = v;
#pragma unroll
                for (int e = 0; e < 8; ++e) f[e] = bf2f(t[e]);
            } else {
                float4 a = *reinterpret_cast<const float4*>((const float*)msrc + i);
                float4 b = *reinterpret_cast<const float4*>((const float*)msrc + i + 4);
                f[0] = a.x; f[1] = a.y; f[2] = a.z; f[3] = a.w;
                f[4] = b.x; f[5] = b.y; f[6] = b.z; f[7] = b.w;
            }
            u16 t[8];
#pragma unroll
            for (int e = 0; e < 8; ++e) t[e] = f2bf(f[e] * 0.125f);
            *reinterpret_cast<uint4*>(maskc + i) = *reinterpret_cast<uint4*>(t);
        }
    }
}

// ---------------------------------------------------------------------------
// Kernel 1: projections GEMM [BN x PD] x [PD x 3072], DMA staging, linear LDS,
// LDS-staged full-line epilogue. grid (BN/128, 3072/128), block 256.
// V output (s==2) is stored FRAGMENT-MAJOR: per (head, 32-token block c,
// d-group dg) a 1KB block holding the 16x16x32 PV A-fragment in lane order
// (lane*16B), with the within-32 key permutation p = quad*8 + h*4 + r for
// token w = h*16 + quad*4 + r. attn reads each fragment as ONE coalesced
// 16B/lane load at base + lane*8 (u16).
__global__ __launch_bounds__(256, 3) void proj_gemm(
    const u16* __restrict__ A,   // ycan [BN][PD]
    const u16* __restrict__ Bm,  // Wcat [3072][PD]
    u16* __restrict__ Xk, u16* __restrict__ Yk, u16* __restrict__ Vtg) {
    int tid = threadIdx.x, lane = tid & 63, w = tid >> 6;
    int mhalf = w & 1, nhalf = w >> 1;
    int m0 = blockIdx.x * 128, n0 = blockIdx.y * 128;
    __shared__ u16 As[128 * 64];
    __shared__ u16 Bs[128 * 64];
    f32x4 acc[4][4] = {};

    for (int kk = 0; kk < PD; kk += 64) {
        __syncthreads();
        stage_dma<128>(A + (size_t)m0 * PD + kk, PD, As, lane, w);
        stage_dma<128>(Bm + (size_t)n0 * PD + kk, PD, Bs, lane, w);
        __syncthreads();
#pragma unroll
        for (int kc = 0; kc < 64; kc += 32) {
            bf16x8 af[4], bf[4];
#pragma unroll
            for (int i = 0; i < 4; ++i) af[i] = ldfragL(As, mhalf * 64 + i * 16, kc, lane);
#pragma unroll
            for (int j = 0; j < 4; ++j) bf[j] = ldfragL(Bs, nhalf * 64 + j * 16, kc, lane);
#pragma unroll
            for (int i = 0; i < 4; ++i)
#pragma unroll
                for (int j = 0; j < 4; ++j) acc[i][j] = mfma_k32(af[i], bf[j], acc[i][j]);
        }
    }
    int s = n0 >> 10;  // tile never crosses the 1024 boundary
    int quad = lane >> 4, col = lane & 15;
    u16* stg = nhalf ? Bs : As;  // this wave-pair's 128x64 output half
    __syncthreads();             // K-loop LDS reads complete
    if (s == 2) {
        // stage fragment-major: local idx = (cLoc*4 + jj)*512 + quad*128 +
        // col*8 + (i&1)*4 + r, where cLoc = mhalf*2 + (i>>1). Global copy is
        // then LINEAR (head_base + m0*64 + idx).
#pragma unroll
        for (int i = 0; i < 4; ++i)
#pragma unroll
            for (int j = 0; j < 4; ++j)
                *reinterpret_cast<bf16x4*>(stg + ((mhalf * 2 + (i >> 1)) * 4 + j) * 512 +
                                           quad * 128 + col * 8 + (i & 1) * 4) =
                    pack4(acc[i][j][0], acc[i][j][1], acc[i][j][2], acc[i][j][3]);
    } else {
        // stage as [tok 128][d 64] (linear = global layout)
#pragma unroll
        for (int i = 0; i < 4; ++i)
#pragma unroll
            for (int j = 0; j < 4; ++j)
#pragma unroll
                for (int reg = 0; reg < 4; ++reg)
                    stg[(mhalf * 64 + i * 16 + quad * 4 + reg) * 64 + j * 16 + col] =
                        f2bf(acc[i][j][reg]);
    }
    __syncthreads();
#pragma unroll
    for (int h = 0; h < 2; ++h) {
        int kh = ((n0 + h * 64) >> 6) & 15;
        const u16* src = h ? Bs : As;
        if (s == 2) {
            u16* vb = Vtg + (size_t)kh * DD * BN + (size_t)m0 * 64;
#pragma unroll
            for (int it = 0; it < 4; ++it) {
                int chunk = it * 256 + tid;  // 1024 uint4, fully linear
                *reinterpret_cast<uint4*>(vb + chunk * 8) =
                    *reinterpret_cast<const uint4*>(src + chunk * 8);
            }
        } else {
            u16* ob = (s == 0 ? Xk : Yk) + (size_t)kh * BN * DD + (size_t)m0 * DD;
#pragma unroll
            for (int it = 0; it < 4; ++it) {
                int chunk = it * 256 + tid;
                *reinterpret_cast<uint4*>(ob + chunk * 8) =
                    *reinterpret_cast<const uint4*>(src + chunk * 8);
            }
        }
    }
}

// ---------------------------------------------------------------------------
// Kernel 2: flash attention v6 — q=32 per wave, ALL 8 waves active.
// Block = 512 thr = 8 waves x 32 q = 256-q tile; grid (2048/256)x16x2 = 256
// blocks = exactly 1 block/CU (no tail). Per-CU K-LDS + V-L1 fragment bytes
// per score HALVE vs q=16 (each wave's 16KB/tile feeds 2x scores), and each
// wave carries 2 independent q-group chains (2x ILP). Registers are free
// (grid caps residency at 8 waves/CU) -> __launch_bounds__(512,2).
// K: LDS triple buffer (reg-staged, padded, one barrier/tile, prefetch 2
// ahead). V: global frag-major via L1. T5 setprio around PV MFMA cluster.
// XCD swizzle: each XCD owns 4 whole (k,b) pairs (K+V 2MB, L2-fits).
__global__ __launch_bounds__(512, 2) void attn_kernel(
    const u16* __restrict__ Xk,     // keys    [KH][BN][DD]
    const u16* __restrict__ Yk,     // queries [KH][BN][DD] prescaled /8
    const u16* __restrict__ Vtg,    // V frag-major [KH][BN/32][4][64*8]
    const u16* __restrict__ maskc,  // [NN][NN] bf16 prescaled /8
    const int* __restrict__ mnz,
    u16* __restrict__ O) {          // [BN][KH*DD]
    int tid = threadIdx.x, lane = tid & 63, w = tid >> 6;  // w in [0,8)
    int quad = lane >> 4, col = lane & 15;
    // XCD swizzle: hw block H (XCD=H%8) -> work L in [32x, 32x+32):
    // XCD x gets 4 (k,b) pairs x 8 q-tiles (shared K/V panels in its L2).
    int H = blockIdx.x;
    int L = (H & 7) * 32 + (H >> 3);
    int q0 = (L & 7) * 256, k = (L >> 3) & 15, b = L >> 7;
    const u16* Qp = Yk + ((size_t)k * BN + b * NN + q0) * DD;
    const u16* Kp = Xk + ((size_t)k * BN + b * NN) * DD;
    const u16* Vh = Vtg + (size_t)k * DD * BN + (size_t)b * NN * 64;
    __shared__ u16 Kb[3][64 * ST];   // K triple buffer (27.6 KB)
    __shared__ u16 Ost[256 * ST];    // output staging (36.9 KB)
    int mz = *mnz;

    // Q B-frags from global: element j = Q[q][quad*8 + j (+32)], q-group qg
    bf16x8 qf[2][2];
#pragma unroll
    for (int qg = 0; qg < 2; ++qg) {
        const u16* qrow = Qp + (size_t)(w * 32 + qg * 16 + col) * DD + (quad << 3);
        qf[qg][0] = *reinterpret_cast<const bf16x8*>(qrow);
        qf[qg][1] = *reinterpret_cast<const bf16x8*>(qrow + 32);
    }

    // K staging slot: one uint4 per thread per tile (64x64 = 512*16B)
    int srow = tid >> 3, scol = (tid & 7) << 3;
    const u16* kgp = Kp + (size_t)srow * DD + scol;
    int soff = srow * ST + scol;

    // prologue: tile 0 -> buf0; tile 1 load in flight
    uint4 kr = *reinterpret_cast<const uint4*>(kgp);
    *reinterpret_cast<uint4*>(Kb[0] + soff) = kr;
    kr = *reinterpret_cast<const uint4*>(kgp + (size_t)64 * DD);
    __syncthreads();  // buf0 visible

    float lp[2] = {0.0f, 0.0f};
    f32x4 oacc[4][2] = {};  // O^T[d][q]: [dg][qg]

    for (int t = 0; t < 32; ++t) {
        int cur = t % 3;
        if (t < 31) {
            int nxt = (t + 1) % 3;
            *reinterpret_cast<uint4*>(Kb[nxt] + soff) = kr;
            __syncthreads();  // buf[nxt] visible
        }
        const u16* Ks = Kb[cur];
        // V A-frags: coalesced 1KB loads (issued early; L1-resident after
        // the first wave touches the tile)
        const u16* vt = Vh + t * 4096;
        bf16x8 av[2][4];
#pragma unroll
        for (int hlf = 0; hlf < 2; ++hlf)
#pragma unroll
            for (int dg = 0; dg < 4; ++dg)
                av[hlf][dg] = *reinterpret_cast<const bf16x8*>(
                    vt + hlf * 2048 + dg * 512 + lane * 8);
        // K reg prefetch 2 tiles ahead
        if (t < 30)
            kr = *reinterpret_cast<const uint4*>(kgp + (size_t)(t + 2) * 64 * DD);
        int m0 = t * 64;

        // S^T[key][q] = K Q^T (prescaled); exp inline per key-group.
        // K-frags shared by both q-groups (the amortization lever).
        bf16x4 pb4[4][2];  // [kg][qg]
#pragma unroll
        for (int kg = 0; kg < 4; ++kg) {
            bf16x8 a0 = ldfrag(Ks, kg * 16, 0, lane);
            bf16x8 a1 = ldfrag(Ks, kg * 16, 32, lane);
#pragma unroll
            for (int qg = 0; qg < 2; ++qg) {
                f32x4 s = {};
                s = mfma_k32(a0, qf[qg][0], s);
                s = mfma_k32(a1, qf[qg][1], s);
                if (mz) {
#pragma unroll
                    for (int reg = 0; reg < 4; ++reg)
                        s[reg] += bf2f(
                            maskc[(size_t)(m0 + kg * 16 + quad * 4 + reg) * NN +
                                  q0 + w * 32 + qg * 16 + col]);
                }
                float p0 = exp2f(fmaf(s[0], LOG2E, -SOFT_C2));
                float p1 = exp2f(fmaf(s[1], LOG2E, -SOFT_C2));
                float p2 = exp2f(fmaf(s[2], LOG2E, -SOFT_C2));
                float p3 = exp2f(fmaf(s[3], LOG2E, -SOFT_C2));
                lp[qg] += (p0 + p1) + (p2 + p3);
                pb4[kg][qg] = pack4(p0, p1, p2, p3);
            }
        }
        // O^T += V^T P^T; A (frag-major V) and B (concat P) share the key
        // perm: slot (quad,j) <-> key = hlf*32 + (j>=4)*16 + quad*4 + (j&3)
        __builtin_amdgcn_s_setprio(1);
#pragma unroll
        for (int hlf = 0; hlf < 2; ++hlf) {
            bf16x8 pb8[2];
#pragma unroll
            for (int qg = 0; qg < 2; ++qg)
                pb8[qg] = __builtin_shufflevector(pb4[hlf * 2][qg],
                                                  pb4[hlf * 2 + 1][qg],
                                                  0, 1, 2, 3, 4, 5, 6, 7);
#pragma unroll
            for (int dg = 0; dg < 4; ++dg)
#pragma unroll
                for (int qg = 0; qg < 2; ++qg)
                    oacc[dg][qg] = mfma_k32(av[hlf][dg], pb8[qg], oacc[dg][qg]);
        }
        __builtin_amdgcn_s_setprio(0);
    }

    // normalize and stage O rows in LDS for full-line global writes
#pragma unroll
    for (int qg = 0; qg < 2; ++qg) {
        float l = lp[qg];
        l += __shfl_xor(l, 16);
        l += __shfl_xor(l, 32);
        float inv = 1.0f / l;
        int q = w * 32 + qg * 16 + col;
#pragma unroll
        for (int dg = 0; dg < 4; ++dg)
            *reinterpret_cast<bf16x4*>(Ost + q * ST + dg * 16 + quad * 4) =
                pack4(oacc[dg][qg][0] * inv, oacc[dg][qg][1] * inv,
                      oacc[dg][qg][2] * inv, oacc[dg][qg][3] * inv);
    }
    __syncthreads();
#pragma unroll
    for (int it = 0; it < 4; ++it) {
        int chunk = it * 512 + tid;  // 2048 uint4 = 256 rows x 64 d
        int row = chunk >> 3, c8 = (chunk & 7) << 3;
        *reinterpret_cast<uint4*>(O + (size_t)(b * NN + q0 + row) * (KH * DD) +
                                  k * DD + c8) =
            *reinterpret_cast<const uint4*>(Ost + row * ST + c8);
    }
}

// ---------------------------------------------------------------------------
// Kernel 3: output projection GEMM [BN x 1024] x [1024 x QD], DMA staging,
// fp32 epilogue staged through LDS for full-line writes.
// grid (BN/128, QD/128), block 256.
__global__ __launch_bounds__(256, 3) void out_gemm(
    const u16* __restrict__ A,   // Ob [BN][KH*DD]
    const u16* __restrict__ Bm,  // ThYr [QD][KH*DD]
    const int* __restrict__ flag,
    void* __restrict__ outv) {
    int tid = threadIdx.x, lane = tid & 63, w = tid >> 6;
    int mhalf = w & 1, nhalf = w >> 1;
    int m0 = blockIdx.x * 128, n0 = blockIdx.y * 128;
    __shared__ u16 S[2][128 * 64];  // As | Bs; reused as fp32 stage (32KB)
    u16* As = S[0];
    u16* Bs = S[1];
    f32x4 acc[4][4] = {};

    for (int kk = 0; kk < KH * DD; kk += 64) {
        __syncthreads();
        stage_dma<128>(A + (size_t)m0 * (KH * DD) + kk, KH * DD, As, lane, w);
        stage_dma<128>(Bm + (size_t)n0 * (KH * DD) + kk, KH * DD, Bs, lane, w);
        __syncthreads();
#pragma unroll
        for (int kc = 0; kc < 64; kc += 32) {
            bf16x8 af[4], bf[4];
#pragma unroll
            for (int i = 0; i < 4; ++i) af[i] = ldfragL(As, mhalf * 64 + i * 16, kc, lane);
#pragma unroll
            for (int j = 0; j < 4; ++j) bf[j] = ldfragL(Bs, nhalf * 64 + j * 16, kc, lane);
#pragma unroll
            for (int i = 0; i < 4; ++i)
#pragma unroll
                for (int j = 0; j < 4; ++j) acc[i][j] = mfma_k32(af[i], bf[j], acc[i][j]);
        }
    }
    int isbf = *flag;
    int quad = lane >> 4, col = lane & 15;
    if (isbf) {
#pragma unroll
        for (int i = 0; i < 4; ++i)
#pragma unroll
            for (int j = 0; j < 4; ++j)
#pragma unroll
                for (int reg = 0; reg < 4; ++reg) {
                    size_t row = m0 + mhalf * 64 + i * 16 + quad * 4 + reg;
                    int c = n0 + nhalf * 64 + j * 16 + col;
                    ((u16*)outv)[row * QD + c] = f2bf(acc[i][j][reg]);
                }
    } else {
        float* Sf = (float*)&S[0][0];  // 64 rows x 128 f32 (32KB)
#pragma unroll
        for (int h = 0; h < 2; ++h) {
            __syncthreads();  // K-loop frag reads / previous copy done
            if (mhalf == h) {
#pragma unroll
                for (int i = 0; i < 4; ++i)
#pragma unroll
                    for (int j = 0; j < 4; ++j)
#pragma unroll
                        for (int reg = 0; reg < 4; ++reg)
                            Sf[(i * 16 + quad * 4 + reg) * 128 + nhalf * 64 +
                               j * 16 + col] = acc[i][j][reg];
            }
            __syncthreads();
            float* orow = (float*)outv + (size_t)(m0 + h * 64) * QD + n0;
#pragma unroll
            for (int it = 0; it < 8; ++it) {
                int chunk = it * 256 + tid;  // 2048 chunks of 4 f32
                int row = chunk >> 5, c4 = (chunk & 31) * 4;
                *reinterpret_cast<float4*>(orow + (size_t)row * QD + c4) =
                    *reinterpret_cast<const float4*>(Sf + row * 128 + c4);
            }
        }
    }
}

// ---------------------------------------------------------------------------
extern "C" void kernel_launch(void* const* d_in, const int* in_sizes, int n_in,
                              void* d_out, int out_size, void* d_ws, size_t ws_size,
                              hipStream_t stream) {
    // ws: flag|mnz 64B; ycan 8.39M (-> Ob after proj); Wcat 3x2.1M; ThYr 2.1M;
    // Xk/Yk/Vtg 8.39M each; maskc 8.39M  => ~50.3 MB
    char* wsb = (char*)d_ws;
    int* flag = (int*)wsb;
    int* mnz = (int*)(wsb + 16);
    u16* ycan = (u16*)(wsb + 64);
    const size_t NYP = (size_t)BN * PD;
    const size_t NW = (size_t)KH * PD * DD;
    const size_t OSZ = (size_t)BN * KH * DD;
    u16* Wcat = ycan + NYP;  // LamXt | LamYt/8 | ThXt contiguous
    u16* ThYr = Wcat + 3 * NW;
    u16* Xk = ThYr + NW;
    u16* Yk = Xk + OSZ;
    u16* Vtg = Yk + OSZ;
    u16* maskc = Vtg + OSZ;
    u16* Ob = ycan;  // aliases ycan (dead after proj_gemm)

    detect_kernel<<<1, 256, 0, stream>>>((const u16*)d_in[0], flag, mnz);
    scan_kernel<<<256, 256, 0, stream>>>(d_in[1], flag, mnz);
    prep_kernel<<<dim3(256, 1, 6), 256, 0, stream>>>(
        d_in[0], d_in[1], d_in[2], d_in[3], d_in[4], d_in[5], ycan, Wcat,
        Wcat + NW, Wcat + 2 * NW, ThYr, maskc, flag, mnz);
    proj_gemm<<<dim3(BN / 128, 3072 / 128), 256, 0, stream>>>(ycan, Wcat, Xk, Yk, Vtg);
    attn_kernel<<<256, 512, 0, stream>>>(Xk, Yk, Vtg, maskc, mnz, Ob);
    out_gemm<<<dim3(BN / 128, QD / 128), 256, 0, stream>>>(Ob, ThYr, flag, d_out);
}

// Round 8
// 230.871 us; speedup vs baseline: 2.1747x; 1.0314x over previous
//
#include <hip/hip_runtime.h>
#include <hip/hip_bf16.h>

// Bilinear multi-head self-attention, MI355X
#define KH 16    // heads
#define PD 1024  // value-in dim
#define QD 1024  // out dim
#define DD 64    // head dim
#define BB 2     // batch
#define NN 2048  // seq len
#define BN 4096  // BB*NN rows
#define ST 72    // padded LDS row stride (u16) for attn
#define SOFT_C 12.0f  // fixed softmax offset: exact (cancels in p/sum p)
#define LOG2E 1.4426950408889634f
#define SOFT_C2 17.312340490667560f  // SOFT_C * log2(e)

typedef unsigned short u16;
typedef __attribute__((ext_vector_type(8))) short bf16x8;  // K=32 A/B frag
typedef __attribute__((ext_vector_type(4))) short bf16x4;  // K=16 A/B frag
typedef __attribute__((ext_vector_type(4))) float f32x4;   // C/D frag

__device__ __forceinline__ float bf2f(u16 u) {
    return __uint_as_float(((unsigned)u) << 16);
}
__device__ __forceinline__ u16 f2bf(float f) {
    unsigned x = __float_as_uint(f);
    x += 0x7FFFu + ((x >> 16) & 1u);  // RNE
    return (u16)(x >> 16);
}
__device__ __forceinline__ f32x4 mfma_k32(bf16x8 a, bf16x8 b, f32x4 c) {
    return __builtin_amdgcn_mfma_f32_16x16x32_bf16(a, b, c, 0, 0, 0);
}
// padded-layout frag (attn K)
__device__ __forceinline__ bf16x8 ldfrag(const u16* base, int r0, int kc, int lane) {
    return *reinterpret_cast<const bf16x8*>(base + (r0 + (lane & 15)) * ST + kc +
                                            ((lane >> 4) << 3));
}
// linear-layout frag (GEMMs, stride 64 u16 — required by global_load_lds DMA)
__device__ __forceinline__ bf16x8 ldfragL(const u16* base, int r0, int kc, int lane) {
    return *reinterpret_cast<const bf16x8*>(base + ((r0 + (lane & 15)) << 6) + kc +
                                            ((lane >> 4) << 3));
}
__device__ __forceinline__ bf16x4 pack4(float a, float b, float c, float d) {
    union { bf16x4 v; __hip_bfloat162 h[2]; } u;
    u.h[0] = __float22bfloat162_rn(make_float2(a, b));
    u.h[1] = __float22bfloat162_rn(make_float2(c, d));
    return u.v;
}
// async global->LDS DMA, 16B/lane; LDS dst = wave-uniform base + lane*16
__device__ __forceinline__ void gl_lds16(const u16* g, u16* l) {
    __builtin_amdgcn_global_load_lds(
        (const __attribute__((address_space(1))) void*)g,
        (__attribute__((address_space(3))) void*)l, 16, 0, 0);
}
// stage ROWSx64 tile (row stride ld) into LINEAR LDS via DMA; 256 threads
template <int ROWS>
__device__ __forceinline__ void stage_dma(const u16* __restrict__ src, int ld,
                                          u16* dst, int lane, int w) {
#pragma unroll
    for (int c = 0; c < ROWS / 32; ++c) {
        int rbase = (w * (ROWS / 32) + c) * 8;
        const u16* g = src + (size_t)(rbase + (lane >> 3)) * ld + ((lane & 7) << 3);
        gl_lds16(g, dst + (rbase << 6));
    }
}

// ---------------------------------------------------------------------------
// dtype detector (+ init mask-nonzero flag to 0)
__global__ void detect_kernel(const u16* __restrict__ y, int* flag, int* mnz) {
    __shared__ int cnt;
    if (threadIdx.x == 0) cnt = 0;
    __syncthreads();
    int local = 0;
    for (int i = threadIdx.x; i < 8192; i += 256) {
        u16 u = y[i];
        int e = (u >> 7) & 0xFF;
        if (u == 0 || (e >= 96 && e < 160)) local++;
    }
    atomicAdd(&cnt, local);
    __syncthreads();
    if (threadIdx.x == 0) {
        *flag = (cnt > 7372) ? 1 : 0;
        *mnz = 0;
    }
}

// mask nonzero scan (bitwise OR of raw words — dtype-independent for zero)
__global__ __launch_bounds__(256) void scan_kernel(const void* __restrict__ msrc,
                                                   const int* __restrict__ flag,
                                                   int* __restrict__ mnz) {
    size_t n4 = (size_t)NN * NN / 8;
    if (!*flag) n4 *= 2;
    const uint4* p = (const uint4*)msrc;
    unsigned acc = 0;
    for (size_t i = (size_t)blockIdx.x * 256 + threadIdx.x; i < n4; i += 256 * 256) {
        uint4 v = p[i];
        acc |= v.x | v.y | v.z | v.w;
    }
    if (acc) atomicOr(mnz, 1);
}

// ---------------------------------------------------------------------------
// fused prepass: grid (256, 1, 6), block 256.
// z=0: convert y (SKIPPED when input already bf16 — proj reads ysrc direct);
// z=1..3: convert+transpose weights ([KH][PD][DD]->[KH][DD][PD], LamY
// prescaled 0.125); z=4: ThY rearrange ([KH][QD][DD]->[QD][KH*DD]);
// z=5: mask convert+prescale (skipped when mask==0).
__global__ __launch_bounds__(256) void prep_kernel(
    const void* __restrict__ ysrc, const void* __restrict__ msrc,
    const void* __restrict__ s0, const void* __restrict__ s1,
    const void* __restrict__ s2, const void* __restrict__ s3,
    u16* __restrict__ ycan, u16* __restrict__ LamXt, u16* __restrict__ LamYt,
    u16* __restrict__ ThXt, u16* __restrict__ ThYr, u16* __restrict__ maskc,
    const int* __restrict__ flag, const int* __restrict__ mnz) {
    int z = blockIdx.z, bx = blockIdx.x, tid = threadIdx.x;
    int isbf = *flag;
    if (z == 0) {  // convert y' (f32 input only; bf16 path reads ysrc direct)
        if (isbf) return;
        int n = BN * PD;
        for (int i = (bx * 256 + tid) * 4; i < n; i += 256 * 256 * 4) {
            float4 f = *reinterpret_cast<const float4*>((const float*)ysrc + i);
            u16 t[4] = {f2bf(f.x), f2bf(f.y), f2bf(f.z), f2bf(f.w)};
            *reinterpret_cast<uint2*>(ycan + i) = *reinterpret_cast<uint2*>(t);
        }
    } else if (z <= 3) {  // weight transpose
        const void* src = (z == 1) ? s0 : (z == 2) ? s1 : s2;
        u16* dst = (z == 1) ? LamXt : (z == 2) ? LamYt : ThXt;
        float scale = (z == 2) ? 0.125f : 1.0f;
        int k = bx >> 4, p0 = (bx & 15) * 64;
        __shared__ float T[64][65];
        const u16* s16 = (const u16*)src + ((size_t)k * PD + p0) * DD;
        const float* s32 = (const float*)src + ((size_t)k * PD + p0) * DD;
#pragma unroll
        for (int it = 0; it < 2; ++it) {
            int chunk = it * 256 + tid;
            int row = chunk >> 3, c8 = (chunk & 7) << 3;
            float f[8];
            if (isbf) {
                uint4 v = *reinterpret_cast<const uint4*>(s16 + row * DD + c8);
                u16 t[8];
                *reinterpret_cast<uint4*>(t) = v;
#pragma unroll
                for (int e = 0; e < 8; ++e) f[e] = bf2f(t[e]);
            } else {
                float4 a = *reinterpret_cast<const float4*>(s32 + row * DD + c8);
                float4 b = *reinterpret_cast<const float4*>(s32 + row * DD + c8 + 4);
                f[0] = a.x; f[1] = a.y; f[2] = a.z; f[3] = a.w;
                f[4] = b.x; f[5] = b.y; f[6] = b.z; f[7] = b.w;
            }
#pragma unroll
            for (int e = 0; e < 8; ++e) T[row][c8 + e] = f[e] * scale;
        }
        __syncthreads();
        u16* drow = dst + (size_t)k * DD * PD + p0;
#pragma unroll
        for (int it = 0; it < 2; ++it) {
            int chunk = it * 256 + tid;
            int d = chunk >> 3, c8 = (chunk & 7) << 3;
            u16 t[8];
#pragma unroll
            for (int e = 0; e < 8; ++e) t[e] = f2bf(T[c8 + e][d]);
            *reinterpret_cast<uint4*>(drow + (size_t)d * PD + c8) =
                *reinterpret_cast<uint4*>(t);
        }
    } else if (z == 4) {  // ThY rearrange
        int k = bx >> 4, q0 = (bx & 15) * 64;
#pragma unroll
        for (int it = 0; it < 2; ++it) {
            int chunk = it * 256 + tid;
            int row = chunk >> 3, c8 = (chunk & 7) << 3;
            size_t si = ((size_t)k * QD + q0 + row) * DD + c8;
            u16 t[8];
            if (isbf) {
                *reinterpret_cast<uint4*>(t) =
                    *reinterpret_cast<const uint4*>((const u16*)s3 + si);
            } else {
                float4 a = *reinterpret_cast<const float4*>((const float*)s3 + si);
                float4 b = *reinterpret_cast<const float4*>((const float*)s3 + si + 4);
                t[0] = f2bf(a.x); t[1] = f2bf(a.y); t[2] = f2bf(a.z); t[3] = f2bf(a.w);
                t[4] = f2bf(b.x); t[5] = f2bf(b.y); t[6] = f2bf(b.z); t[7] = f2bf(b.w);
            }
            *reinterpret_cast<uint4*>(ThYr + (size_t)(q0 + row) * (KH * DD) +
                                      k * DD + c8) = *reinterpret_cast<uint4*>(t);
        }
    } else {  // z == 5: mask convert + prescale (only if mask nonzero)
        if (*mnz == 0) return;
        size_t n8 = (size_t)NN * NN / 8;
        for (size_t c = (size_t)bx * 256 + tid; c < n8; c += 256 * 256) {
            size_t i = c * 8;
            float f[8];
            if (isbf) {
                uint4 v = *reinterpret_cast<const uint4*>((const u16*)msrc + i);
                u16 t[8];
                *reinterpret_cast<uint4*>(t) = v;
#pragma unroll
                for (int e = 0; e < 8; ++e) f[e] = bf2f(t[e]);
            } else {
                float4 a = *reinterpret_cast<const float4*>((const float*)msrc + i);
                float4 b = *reinterpret_cast<const float4*>((const float*)msrc + i + 4);
                f[0] = a.x; f[1] = a.y; f[2] = a.z; f[3] = a.w;
                f[4] = b.x; f[5] = b.y; f[6] = b.z; f[7] = b.w;
            }
            u16 t[8];
#pragma unroll
            for (int e = 0; e < 8; ++e) t[e] = f2bf(f[e] * 0.125f);
            *reinterpret_cast<uint4*>(maskc + i) = *reinterpret_cast<uint4*>(t);
        }
    }
}

// ---------------------------------------------------------------------------
// Kernel 1: projections GEMM [BN x PD] x [PD x 3072], DMA staging, linear LDS,
// LDS-staged full-line epilogue. grid (BN/128, 3072/128), block 256.
// A source: ysrc directly when input is bf16 (skips the ycan copy pass).
// V output (s==2) is stored FRAGMENT-MAJOR: per (head, 32-token block c,
// d-group dg) a 1KB block holding the 16x16x32 PV A-fragment in lane order
// (lane*16B), with the within-32 key permutation p = quad*8 + h*4 + r for
// token w = h*16 + quad*4 + r. attn reads each fragment as ONE coalesced
// 16B/lane load at base + lane*8 (u16).
__global__ __launch_bounds__(256, 3) void proj_gemm(
    const u16* __restrict__ Acan,  // ycan [BN][PD] (f32-input path)
    const void* __restrict__ ysrc, // raw input (bf16 path reads direct)
    const int* __restrict__ flag,
    const u16* __restrict__ Bm,    // Wcat [3072][PD]
    u16* __restrict__ Xk, u16* __restrict__ Yk, u16* __restrict__ Vtg) {
    int tid = threadIdx.x, lane = tid & 63, w = tid >> 6;
    int mhalf = w & 1, nhalf = w >> 1;
    int m0 = blockIdx.x * 128, n0 = blockIdx.y * 128;
    const u16* A = (*flag) ? (const u16*)ysrc : Acan;
    __shared__ u16 As[128 * 64];
    __shared__ u16 Bs[128 * 64];
    f32x4 acc[4][4] = {};

    for (int kk = 0; kk < PD; kk += 64) {
        __syncthreads();
        stage_dma<128>(A + (size_t)m0 * PD + kk, PD, As, lane, w);
        stage_dma<128>(Bm + (size_t)n0 * PD + kk, PD, Bs, lane, w);
        __syncthreads();
#pragma unroll
        for (int kc = 0; kc < 64; kc += 32) {
            bf16x8 af[4], bf[4];
#pragma unroll
            for (int i = 0; i < 4; ++i) af[i] = ldfragL(As, mhalf * 64 + i * 16, kc, lane);
#pragma unroll
            for (int j = 0; j < 4; ++j) bf[j] = ldfragL(Bs, nhalf * 64 + j * 16, kc, lane);
#pragma unroll
            for (int i = 0; i < 4; ++i)
#pragma unroll
                for (int j = 0; j < 4; ++j) acc[i][j] = mfma_k32(af[i], bf[j], acc[i][j]);
        }
    }
    int s = n0 >> 10;  // tile never crosses the 1024 boundary
    int quad = lane >> 4, col = lane & 15;
    u16* stg = nhalf ? Bs : As;  // this wave-pair's 128x64 output half
    __syncthreads();             // K-loop LDS reads complete
    if (s == 2) {
        // stage fragment-major: local idx = (cLoc*4 + jj)*512 + quad*128 +
        // col*8 + (i&1)*4 + r, where cLoc = mhalf*2 + (i>>1). Global copy is
        // then LINEAR (head_base + m0*64 + idx).
#pragma unroll
        for (int i = 0; i < 4; ++i)
#pragma unroll
            for (int j = 0; j < 4; ++j)
                *reinterpret_cast<bf16x4*>(stg + ((mhalf * 2 + (i >> 1)) * 4 + j) * 512 +
                                           quad * 128 + col * 8 + (i & 1) * 4) =
                    pack4(acc[i][j][0], acc[i][j][1], acc[i][j][2], acc[i][j][3]);
    } else {
        // stage as [tok 128][d 64] (linear = global layout)
#pragma unroll
        for (int i = 0; i < 4; ++i)
#pragma unroll
            for (int j = 0; j < 4; ++j)
#pragma unroll
                for (int reg = 0; reg < 4; ++reg)
                    stg[(mhalf * 64 + i * 16 + quad * 4 + reg) * 64 + j * 16 + col] =
                        f2bf(acc[i][j][reg]);
    }
    __syncthreads();
#pragma unroll
    for (int h = 0; h < 2; ++h) {
        int kh = ((n0 + h * 64) >> 6) & 15;
        const u16* src = h ? Bs : As;
        if (s == 2) {
            u16* vb = Vtg + (size_t)kh * DD * BN + (size_t)m0 * 64;
#pragma unroll
            for (int it = 0; it < 4; ++it) {
                int chunk = it * 256 + tid;  // 1024 uint4, fully linear
                *reinterpret_cast<uint4*>(vb + chunk * 8) =
                    *reinterpret_cast<const uint4*>(src + chunk * 8);
            }
        } else {
            u16* ob = (s == 0 ? Xk : Yk) + (size_t)kh * BN * DD + (size_t)m0 * DD;
#pragma unroll
            for (int it = 0; it < 4; ++it) {
                int chunk = it * 256 + tid;
                *reinterpret_cast<uint4*>(ob + chunk * 8) =
                    *reinterpret_cast<const uint4*>(src + chunk * 8);
            }
        }
    }
}

// ---------------------------------------------------------------------------
// Kernel 2: flash attention v7 — R3 body re-tiled to 4-wave blocks.
// Block = 256 thr = 4 waves x 16 q = 64-q tile; grid 32x16x2 = 1024 blocks
// = 4 blocks/CU. Same 16 waves/CU as R3 but FOUR independent barrier groups
// per CU (vs R3's two): when one group waits at its tile barrier, others
// issue — targets the lockstep-latency diagnosis confirmed by R6's negative
// (8 waves/CU = 85us) and R3's 16-wave 69us. Per-wave work identical to R3.
// K: LDS triple buffer (reg-staged 2 chunks/thread, padded). V: global
// frag-major via L1. T5 setprio around PV MFMA cluster. XCD swizzle: each
// XCD owns 4 whole (k,b) pairs (K+V 2MB, L2-fits).
__global__ __launch_bounds__(256, 4) void attn_kernel(
    const u16* __restrict__ Xk,     // keys    [KH][BN][DD]
    const u16* __restrict__ Yk,     // queries [KH][BN][DD] prescaled /8
    const u16* __restrict__ Vtg,    // V frag-major [KH][BN/32][4][64*8]
    const u16* __restrict__ maskc,  // [NN][NN] bf16 prescaled /8
    const int* __restrict__ mnz,
    u16* __restrict__ O) {          // [BN][KH*DD]
    int tid = threadIdx.x, lane = tid & 63, w = tid >> 6;  // w in [0,4)
    int quad = lane >> 4, col = lane & 15;
    // XCD swizzle: hw block H (XCD=H%8) -> work L in [128x, 128x+128):
    // XCD x gets 4 (k,b) pairs x 32 q-tiles (shared K/V panels in its L2).
    int H = blockIdx.x;
    int L = (H & 7) * 128 + (H >> 3);
    int q0 = (L & 31) * 64, k = (L >> 5) & 15, b = L >> 9;
    const u16* Qp = Yk + ((size_t)k * BN + b * NN + q0) * DD;
    const u16* Kp = Xk + ((size_t)k * BN + b * NN) * DD;
    const u16* Vh = Vtg + (size_t)k * DD * BN + (size_t)b * NN * 64;
    __shared__ u16 Kb[3][64 * ST];  // K triple buffer (27.6 KB)
    __shared__ u16 Ost[64 * ST];    // output staging (9.2 KB)
    int mz = *mnz;

    // Q B-frags from global: element j = Q[q][quad*8 + j (+32)]
    const u16* qrow = Qp + (size_t)(w * 16 + col) * DD + (quad << 3);
    bf16x8 qf0 = *reinterpret_cast<const bf16x8*>(qrow);
    bf16x8 qf1 = *reinterpret_cast<const bf16x8*>(qrow + 32);

    // K staging: 64x64 tile = 512 uint4 chunks, 2 per thread (rows r, r+32)
    int srow = tid >> 3, scol = (tid & 7) << 3;
    const u16* kgp = Kp + (size_t)srow * DD + scol;
    int soff = srow * ST + scol;

    // prologue: tile 0 -> buf0; tile 1 loads in flight
    uint4 kr0 = *reinterpret_cast<const uint4*>(kgp);
    uint4 kr1 = *reinterpret_cast<const uint4*>(kgp + (size_t)32 * DD);
    *reinterpret_cast<uint4*>(Kb[0] + soff) = kr0;
    *reinterpret_cast<uint4*>(Kb[0] + soff + 32 * ST) = kr1;
    kr0 = *reinterpret_cast<const uint4*>(kgp + (size_t)64 * DD);
    kr1 = *reinterpret_cast<const uint4*>(kgp + (size_t)96 * DD);
    __syncthreads();  // buf0 visible

    float lp = 0.0f;
    f32x4 oacc[4] = {};  // O^T[d][q] d-groups

    for (int t = 0; t < 32; ++t) {
        int cur = t % 3;
        if (t < 31) {
            int nxt = (t + 1) % 3;
            *reinterpret_cast<uint4*>(Kb[nxt] + soff) = kr0;
            *reinterpret_cast<uint4*>(Kb[nxt] + soff + 32 * ST) = kr1;
            __syncthreads();  // buf[nxt] visible
        }
        const u16* Ks = Kb[cur];
        // V A-frags: coalesced 1KB loads (L1-resident after first wave)
        const u16* vt = Vh + t * 4096;
        bf16x8 av[2][4];
#pragma unroll
        for (int hlf = 0; hlf < 2; ++hlf)
#pragma unroll
            for (int dg = 0; dg < 4; ++dg)
                av[hlf][dg] = *reinterpret_cast<const bf16x8*>(
                    vt + hlf * 2048 + dg * 512 + lane * 8);
        // K reg prefetch 2 tiles ahead
        if (t < 30) {
            const u16* knb = kgp + (size_t)(t + 2) * 64 * DD;
            kr0 = *reinterpret_cast<const uint4*>(knb);
            kr1 = *reinterpret_cast<const uint4*>(knb + (size_t)32 * DD);
        }
        int m0 = t * 64;

        // S^T[key][q] = K Q^T (prescaled); exp inline per key-group
        bf16x4 pb4[4];
#pragma unroll
        for (int kg = 0; kg < 4; ++kg) {
            bf16x8 a0 = ldfrag(Ks, kg * 16, 0, lane);
            bf16x8 a1 = ldfrag(Ks, kg * 16, 32, lane);
            f32x4 s = {};
            s = mfma_k32(a0, qf0, s);
            s = mfma_k32(a1, qf1, s);
            if (mz) {
#pragma unroll
                for (int reg = 0; reg < 4; ++reg)
                    s[reg] += bf2f(
                        maskc[(size_t)(m0 + kg * 16 + quad * 4 + reg) * NN + q0 +
                              w * 16 + col]);
            }
            float p0 = exp2f(fmaf(s[0], LOG2E, -SOFT_C2));
            float p1 = exp2f(fmaf(s[1], LOG2E, -SOFT_C2));
            float p2 = exp2f(fmaf(s[2], LOG2E, -SOFT_C2));
            float p3 = exp2f(fmaf(s[3], LOG2E, -SOFT_C2));
            lp += (p0 + p1) + (p2 + p3);
            pb4[kg] = pack4(p0, p1, p2, p3);
        }
        // O^T += V^T P^T; A (frag-major V) and B (concat P) share the key
        // perm: slot (quad,j) <-> key = hlf*32 + (j>=4)*16 + quad*4 + (j&3)
        __builtin_amdgcn_s_setprio(1);
#pragma unroll
        for (int hlf = 0; hlf < 2; ++hlf) {
            bf16x8 pb8 = __builtin_shufflevector(pb4[hlf * 2], pb4[hlf * 2 + 1],
                                                 0, 1, 2, 3, 4, 5, 6, 7);
#pragma unroll
            for (int dg = 0; dg < 4; ++dg)
                oacc[dg] = mfma_k32(av[hlf][dg], pb8, oacc[dg]);
        }
        __builtin_amdgcn_s_setprio(0);
    }

    // normalize and stage O rows in LDS for full-line global writes
    float l = lp;
    l += __shfl_xor(l, 16);
    l += __shfl_xor(l, 32);
    float inv = 1.0f / l;
    int q = w * 16 + col;
#pragma unroll
    for (int dg = 0; dg < 4; ++dg)
        *reinterpret_cast<bf16x4*>(Ost + q * ST + dg * 16 + quad * 4) =
            pack4(oacc[dg][0] * inv, oacc[dg][1] * inv, oacc[dg][2] * inv,
                  oacc[dg][3] * inv);
    __syncthreads();
#pragma unroll
    for (int it = 0; it < 2; ++it) {
        int chunk = it * 256 + tid;  // 512 uint4 = 64 rows x 64 d
        int row = chunk >> 3, c8 = (chunk & 7) << 3;
        *reinterpret_cast<uint4*>(O + (size_t)(b * NN + q0 + row) * (KH * DD) +
                                  k * DD + c8) =
            *reinterpret_cast<const uint4*>(Ost + row * ST + c8);
    }
}

// ---------------------------------------------------------------------------
// Kernel 3: output projection GEMM [BN x 1024] x [1024 x QD], DMA staging,
// fp32 epilogue staged through LDS for full-line writes.
// grid (BN/128, QD/128), block 256.
__global__ __launch_bounds__(256, 3) void out_gemm(
    const u16* __restrict__ A,   // Ob [BN][KH*DD]
    const u16* __restrict__ Bm,  // ThYr [QD][KH*DD]
    const int* __restrict__ flag,
    void* __restrict__ outv) {
    int tid = threadIdx.x, lane = tid & 63, w = tid >> 6;
    int mhalf = w & 1, nhalf = w >> 1;
    int m0 = blockIdx.x * 128, n0 = blockIdx.y * 128;
    __shared__ u16 S[2][128 * 64];  // As | Bs; reused as fp32 stage (32KB)
    u16* As = S[0];
    u16* Bs = S[1];
    f32x4 acc[4][4] = {};

    for (int kk = 0; kk < KH * DD; kk += 64) {
        __syncthreads();
        stage_dma<128>(A + (size_t)m0 * (KH * DD) + kk, KH * DD, As, lane, w);
        stage_dma<128>(Bm + (size_t)n0 * (KH * DD) + kk, KH * DD, Bs, lane, w);
        __syncthreads();
#pragma unroll
        for (int kc = 0; kc < 64; kc += 32) {
            bf16x8 af[4], bf[4];
#pragma unroll
            for (int i = 0; i < 4; ++i) af[i] = ldfragL(As, mhalf * 64 + i * 16, kc, lane);
#pragma unroll
            for (int j = 0; j < 4; ++j) bf[j] = ldfragL(Bs, nhalf * 64 + j * 16, kc, lane);
#pragma unroll
            for (int i = 0; i < 4; ++i)
#pragma unroll
                for (int j = 0; j < 4; ++j) acc[i][j] = mfma_k32(af[i], bf[j], acc[i][j]);
        }
    }
    int isbf = *flag;
    int quad = lane >> 4, col = lane & 15;
    if (isbf) {
#pragma unroll
        for (int i = 0; i < 4; ++i)
#pragma unroll
            for (int j = 0; j < 4; ++j)
#pragma unroll
                for (int reg = 0; reg < 4; ++reg) {
                    size_t row = m0 + mhalf * 64 + i * 16 + quad * 4 + reg;
                    int c = n0 + nhalf * 64 + j * 16 + col;
                    ((u16*)outv)[row * QD + c] = f2bf(acc[i][j][reg]);
                }
    } else {
        float* Sf = (float*)&S[0][0];  // 64 rows x 128 f32 (32KB)
#pragma unroll
        for (int h = 0; h < 2; ++h) {
            __syncthreads();  // K-loop frag reads / previous copy done
            if (mhalf == h) {
#pragma unroll
                for (int i = 0; i < 4; ++i)
#pragma unroll
                    for (int j = 0; j < 4; ++j)
#pragma unroll
                        for (int reg = 0; reg < 4; ++reg)
                            Sf[(i * 16 + quad * 4 + reg) * 128 + nhalf * 64 +
                               j * 16 + col] = acc[i][j][reg];
            }
            __syncthreads();
            float* orow = (float*)outv + (size_t)(m0 + h * 64) * QD + n0;
#pragma unroll
            for (int it = 0; it < 8; ++it) {
                int chunk = it * 256 + tid;  // 2048 chunks of 4 f32
                int row = chunk >> 5, c4 = (chunk & 31) * 4;
                *reinterpret_cast<float4*>(orow + (size_t)row * QD + c4) =
                    *reinterpret_cast<const float4*>(Sf + row * 128 + c4);
            }
        }
    }
}

// ---------------------------------------------------------------------------
extern "C" void kernel_launch(void* const* d_in, const int* in_sizes, int n_in,
                              void* d_out, int out_size, void* d_ws, size_t ws_size,
                              hipStream_t stream) {
    // ws: flag|mnz 64B; ycan 8.39M (-> Ob after proj); Wcat 3x2.1M; ThYr 2.1M;
    // Xk/Yk/Vtg 8.39M each; maskc 8.39M  => ~50.3 MB
    char* wsb = (char*)d_ws;
    int* flag = (int*)wsb;
    int* mnz = (int*)(wsb + 16);
    u16* ycan = (u16*)(wsb + 64);
    const size_t NYP = (size_t)BN * PD;
    const size_t NW = (size_t)KH * PD * DD;
    const size_t OSZ = (size_t)BN * KH * DD;
    u16* Wcat = ycan + NYP;  // LamXt | LamYt/8 | ThXt contiguous
    u16* ThYr = Wcat + 3 * NW;
    u16* Xk = ThYr + NW;
    u16* Yk = Xk + OSZ;
    u16* Vtg = Yk + OSZ;
    u16* maskc = Vtg + OSZ;
    u16* Ob = ycan;  // aliases ycan (dead after proj_gemm)

    detect_kernel<<<1, 256, 0, stream>>>((const u16*)d_in[0], flag, mnz);
    scan_kernel<<<256, 256, 0, stream>>>(d_in[1], flag, mnz);
    prep_kernel<<<dim3(256, 1, 6), 256, 0, stream>>>(
        d_in[0], d_in[1], d_in[2], d_in[3], d_in[4], d_in[5], ycan, Wcat,
        Wcat + NW, Wcat + 2 * NW, ThYr, maskc, flag, mnz);
    proj_gemm<<<dim3(BN / 128, 3072 / 128), 256, 0, stream>>>(
        ycan, d_in[0], flag, Wcat, Xk, Yk, Vtg);
    attn_kernel<<<1024, 256, 0, stream>>>(Xk, Yk, Vtg, maskc, mnz, Ob);
    out_gemm<<<dim3(BN / 128, QD / 128), 256, 0, stream>>>(Ob, ThYr, flag, d_out);
}